// Round 14
// baseline (233.619 us; speedup 1.0000x reference)
//
#include <hip/hip_runtime.h>
#include <hip/hip_bf16.h>
#include <math.h>

// Problem: MultiHeadSelfAttention  B=4, S=2048, D=1024, H=16, Hd=64
// fp32 in / fp32 out. bf16 scratch, fp32 accumulation.
// Round 23:
//  - gemm_qkv: fp32-A fused conversion (deletes cvt_bf16(x) kernel, -48MB
//    stream traffic). A staged global(fp32)->reg -> v_cvt_pk_bf16_f32 ->
//    ds_write_b128 into the SAME LDS layout as gl_lds (frag reads
//    untouched). Ring-3 schedule re-derived: per step outstanding at wait
//    = {B(t), A(t+1)x4, B(t+1)} = 6 -> vmcnt(1); lgkmcnt(0) before each
//    barrier for ds_write visibility. Loads(t+2) at step t, cvt+write at
//    t+1, compute at t+2 (ring-3 slack). B path unchanged (gl_lds).
//  - attn: R22-verified (T14 async-stage + dbuf), frozen.
//  - gemm_out: R18/R21-verified 128^2/4w, frozen.
// ws: Qb@0, Kb@16M, Vb@32M, Ob@48M. Wstash in d_out (dead until final
// GEMM); wo converted into Qb after attention frees it.

#define S_LEN 2048
#define DM    1024
#define NH    16
#define HD    64
#define M_ROWS 8192   // B * S

typedef __attribute__((ext_vector_type(8))) short bf16x8;
typedef __attribute__((ext_vector_type(4))) float f32x4;
typedef __attribute__((ext_vector_type(16))) float f32x16;

__device__ __forceinline__ float bf2f(unsigned short u) {
  union { unsigned int i; float f; } c; c.i = ((unsigned int)u) << 16; return c.f;
}
__device__ __forceinline__ unsigned short f2bf(float f) {
  unsigned int x = __float_as_uint(f);
  if ((x & 0x7fffffffu) > 0x7f800000u) return (unsigned short)0x7fc0u;  // NaN
  return (unsigned short)((x + 0x7fffu + ((x >> 16) & 1u)) >> 16);      // RNE
}
// packed fp32x2 -> bf16x2 (RNE); dst.lo = cvt(a), dst.hi = cvt(b)
__device__ __forceinline__ unsigned int cvtpk(float a, float b) {
  unsigned int r;
  asm("v_cvt_pk_bf16_f32 %0, %1, %2" : "=v"(r) : "v"(a), "v"(b));
  return r;
}
// async global->LDS, 16 B per lane; lds dest must be wave-uniform
__device__ __forceinline__ void gl_lds16(const unsigned short* g, unsigned short* l) {
  __builtin_amdgcn_global_load_lds(
      (const __attribute__((address_space(1))) unsigned int*)g,
      (__attribute__((address_space(3))) unsigned int*)l, 16, 0, 0);
}

#define FENCE() asm volatile("" ::: "memory")

// ---------------------------------------------------------------------------
// fp32 -> bf16 bulk convert (8 elems/thread) — used for wo only
// ---------------------------------------------------------------------------
__global__ __launch_bounds__(256) void cvt_bf16(const float* __restrict__ in,
                                                unsigned short* __restrict__ out) {
  const int i = blockIdx.x * 256 + threadIdx.x;
  float4 a = ((const float4*)in)[2 * i];
  float4 b = ((const float4*)in)[2 * i + 1];
  ushort4 r0, r1;
  r0.x = f2bf(a.x); r0.y = f2bf(a.y); r0.z = f2bf(a.z); r0.w = f2bf(a.w);
  r1.x = f2bf(b.x); r1.y = f2bf(b.y); r1.z = f2bf(b.z); r1.w = f2bf(b.w);
  ((ushort4*)out)[2 * i] = r0;
  ((ushort4*)out)[2 * i + 1] = r1;
}

// convert wq,wk,wv (1M fp32 each) into one contiguous bf16 stash [3072][1024]
__global__ __launch_bounds__(256) void cvt_w3(const float* __restrict__ w0,
                                              const float* __restrict__ w1,
                                              const float* __restrict__ w2,
                                              unsigned short* __restrict__ out) {
  const int idx = blockIdx.x;                 // 0..1535
  const int which = idx >> 9;
  const float* src = (which == 0) ? w0 : (which == 1) ? w1 : w2;
  unsigned short* dst = out + (size_t)which * (DM * DM);
  const int i = (idx & 511) * 256 + threadIdx.x;
  float4 a = ((const float4*)src)[2 * i];
  float4 b = ((const float4*)src)[2 * i + 1];
  ushort4 r0, r1;
  r0.x = f2bf(a.x); r0.y = f2bf(a.y); r0.z = f2bf(a.z); r0.w = f2bf(a.w);
  r1.x = f2bf(b.x); r1.y = f2bf(b.y); r1.z = f2bf(b.z); r1.w = f2bf(b.w);
  ((ushort4*)dst)[2 * i] = r0;
  ((ushort4*)dst)[2 * i + 1] = r1;
}

// ---------------------------------------------------------------------------
// QKV GEMM, fp32-A fused conversion. C[m,e] = sum_d X[m,d] * Wall[e,d].
// 256x128, BK=32, 8 waves; ring-3; 1 barrier/K-step.
// A: global fp32 -> regs (4x dwordx4/wave/tile) -> cvt_pk -> 2x ds_write_b128
//    (LDS layout identical to the old gl_lds placement).
// B: gl_lds16 (unchanged).
// Step t: vmcnt(1) [drains B(t)+A(t+1)x4, keeps B(t+1)] -> lgkm(0) -> bar
//   -> CVTWR A(t+1) into buf (t+1)%3 -> LDA(t+2) -> STB(t+2) -> COMPUTE(t).
// ---------------------------------------------------------------------------
__global__ __launch_bounds__(512, 4) void gemm_qkv(const float* __restrict__ Xf,
                                                   const unsigned short* __restrict__ Wall,
                                                   unsigned short* __restrict__ outB) {
  __shared__ __align__(16) unsigned short As[3 * 8192];  // [buf][kgrp4][256][8]
  __shared__ __align__(16) unsigned short Bs[3 * 4096];  // [buf][kgrp4][128][8]
  const int m0 = blockIdx.x * 256;
  const int n0 = blockIdx.y * 128;
  const int tid = threadIdx.x;
  const int lane = tid & 63, w = tid >> 6;
  const int quad = lane >> 4, l15 = lane & 15;
  const int wrow = w >> 1, wcol = w & 1;    // compute mapping: 4M x 2N waves

  // staging map: wave w owns kgrp skg, row-quarter srq (rows srq*64 & +128)
  const int skg = w & 3, srq = w >> 2;
  const float* axA = Xf + (size_t)(m0 + srq * 64 + lane) * DM + skg * 8;
  const unsigned short* bgB = Wall + (size_t)(n0 + srq * 64 + lane) * DM + skg * 8;
  const int lA0 = skg * 2048 + srq * 512 + lane * 8;  // per-lane elem offset
  const int lA1 = lA0 + 1024;                          // rows +128
  const int lB  = skg * 1024 + srq * 512;              // wave-uniform (gl_lds)
  const int raA = quad * 2048 + (wrow * 64 + l15) * 8; // frag-read bases
  const int raB = quad * 1024 + (wcol * 64 + l15) * 8;

  f32x4 acc[4][4];
#pragma unroll
  for (int i = 0; i < 4; ++i)
#pragma unroll
    for (int j = 0; j < 4; ++j) { acc[i][j].x = 0.f; acc[i][j].y = 0.f; acc[i][j].z = 0.f; acc[i][j].w = 0.f; }

  float4 fa0, fb0, fa1, fb1;   // in-flight A fp32 regs (one tile)

#define LDA(T) do {                                                          \
    const float* p_ = axA + (size_t)(T) * 32;                                \
    fa0 = *(const float4*)(p_);                                              \
    fb0 = *(const float4*)(p_ + 4);                                          \
    fa1 = *(const float4*)(p_ + 128 * DM);                                   \
    fb1 = *(const float4*)(p_ + 128 * DM + 4);                               \
  } while (0)

#define CVTWR(WB) do {                                                       \
    uint4 u_;                                                                \
    u_.x = cvtpk(fa0.x, fa0.y); u_.y = cvtpk(fa0.z, fa0.w);                  \
    u_.z = cvtpk(fb0.x, fb0.y); u_.w = cvtpk(fb0.z, fb0.w);                  \
    *(uint4*)&As[(WB) * 8192 + lA0] = u_;                                    \
    u_.x = cvtpk(fa1.x, fa1.y); u_.y = cvtpk(fa1.z, fa1.w);                  \
    u_.z = cvtpk(fb1.x, fb1.y); u_.w = cvtpk(fb1.z, fb1.w);                  \
    *(uint4*)&As[(WB) * 8192 + lA1] = u_;                                    \
  } while (0)

#define STB(T, SB) gl_lds16(bgB + (size_t)(T) * 32, &Bs[(SB) * 4096 + lB])

#define COMPUTE(CB) do {                                                     \
    bf16x8 af_[4], bq_[4];                                                   \
    _Pragma("unroll")                                                        \
    for (int mi = 0; mi < 4; ++mi)                                           \
      af_[mi] = *(const bf16x8*)&As[(CB) * 8192 + raA + mi * 128];           \
    _Pragma("unroll")                                                        \
    for (int ni = 0; ni < 4; ++ni)                                           \
      bq_[ni] = *(const bf16x8*)&Bs[(CB) * 4096 + raB + ni * 128];           \
    __builtin_amdgcn_s_setprio(1);                                           \
    _Pragma("unroll")                                                        \
    for (int mi = 0; mi < 4; ++mi)                                           \
      _Pragma("unroll")                                                      \
      for (int ni = 0; ni < 4; ++ni)                                         \
        acc[mi][ni] = __builtin_amdgcn_mfma_f32_16x16x32_bf16(af_[mi], bq_[ni], acc[mi][ni], 0, 0, 0); \
    __builtin_amdgcn_s_setprio(0);                                           \
  } while (0)

#define SUBSTEP(T, CB, WB, SB) do {                                          \
    asm volatile("s_waitcnt vmcnt(1)" ::: "memory");                         \
    asm volatile("s_waitcnt lgkmcnt(0)" ::: "memory");                       \
    __builtin_amdgcn_s_barrier();                                            \
    FENCE();                                                                 \
    CVTWR(WB);                                                               \
    LDA((T) + 2);                                                            \
    FENCE();                                                                 \
    STB((T) + 2, SB);                                                        \
    FENCE();                                                                 \
    COMPUTE(CB);                                                             \
    FENCE();                                                                 \
  } while (0)

  // prologue: A(0)+B(0) issued; A(0) cvt->buf0; A(1)+B(1) issued.
  // invariant entering t=0: outstanding = {B(0), A(1)x4, B(1)} = 6.
  LDA(0);
  FENCE();
  STB(0, 0);
  FENCE();
  asm volatile("s_waitcnt vmcnt(1)" ::: "memory");   // A(0) landed
  CVTWR(0);
  LDA(1);
  FENCE();
  STB(1, 1);
  FENCE();

  // main loop: t = 0..29 (CB cycles 0,1,2; WB=(t+1)%3; SB=(t+2)%3)
  for (int t = 0; t < 30; t += 3) {
    SUBSTEP(t,     0, 1, 2);
    SUBSTEP(t + 1, 1, 2, 0);
    SUBSTEP(t + 2, 2, 0, 1);
  }
  // tail t=30: outstanding {B(30), A(31)x4, B(31)} -> vmcnt(1)
  asm volatile("s_waitcnt vmcnt(1)" ::: "memory");
  asm volatile("s_waitcnt lgkmcnt(0)" ::: "memory");
  __builtin_amdgcn_s_barrier();
  FENCE();
  CVTWR(1);          // A(31) -> buf 31%3 = 1
  FENCE();
  COMPUTE(0);
  FENCE();
  // tail t=31: outstanding {B(31)} -> vmcnt(0)
  asm volatile("s_waitcnt vmcnt(0)" ::: "memory");
  asm volatile("s_waitcnt lgkmcnt(0)" ::: "memory");
  __builtin_amdgcn_s_barrier();
  FENCE();
  COMPUTE(1);

#undef SUBSTEP
#undef COMPUTE
#undef STB
#undef CVTWR
#undef LDA

  const float oscale = (n0 < 1024) ? 0.125f : 1.0f;
#pragma unroll
  for (int mi = 0; mi < 4; ++mi) {
#pragma unroll
    for (int reg = 0; reg < 4; ++reg) {
      const int m = m0 + wrow * 64 + mi * 16 + quad * 4 + reg;
#pragma unroll
      for (int ni = 0; ni < 4; ++ni) {
        const int e = n0 + wcol * 64 + ni * 16 + l15;
        const float v = acc[mi][ni][reg];
        const int z = e >> 10;                   // 0:Q 1:K 2:V
        const int e10 = e & 1023;
        const int b = m >> 11, s = m & (S_LEN - 1);
        const int h = e10 >> 6, hd = e10 & 63;
        outB[(size_t)z * (M_ROWS * DM) +
             (((size_t)(b * NH + h)) * S_LEN + s) * HD + hd] = f2bf(v * oscale);
      }
    }
  }
}

// ---------------------------------------------------------------------------
// Final GEMM (R18/R21-verified 128^2/4w): counted-vmcnt ring-3, fp32 out.
// ---------------------------------------------------------------------------
__global__ __launch_bounds__(256, 2) void gemm_out(const unsigned short* __restrict__ A,
                                                   const unsigned short* __restrict__ Wb,
                                                   float* __restrict__ outF) {
  __shared__ __align__(16) unsigned short As[3 * 4096];  // [buf][kgrp4][128][8]
  __shared__ __align__(16) unsigned short Bs[3 * 4096];
  const int m0 = blockIdx.x * 128;
  const int n0 = blockIdx.y * 128;
  const int tid = threadIdx.x;
  const int lane = tid & 63, w = tid >> 6;   // 4 waves
  const int quad = lane >> 4, l15 = lane & 15;
  const int wr = w >> 1, wc = w & 1;         // compute mapping: 2M x 2N waves

  const unsigned short* agA = A  + (size_t)(m0 + lane) * DM + w * 8;
  const unsigned short* bgB = Wb + (size_t)(n0 + lane) * DM + w * 8;
  const int lA0 = w * 1024;                  // elem base (kgrp=w, rows 0..63)
  const int lB0 = w * 1024;
  const int raA = quad * 1024 + (wr * 64 + l15) * 8;  // frag-read bases
  const int raB = quad * 1024 + (wc * 64 + l15) * 8;

  f32x4 acc[4][4];
#pragma unroll
  for (int i = 0; i < 4; ++i)
#pragma unroll
    for (int j = 0; j < 4; ++j) { acc[i][j].x = 0.f; acc[i][j].y = 0.f; acc[i][j].z = 0.f; acc[i][j].w = 0.f; }

#define STAGE4(T, SB) do {                                                   \
    const unsigned short* ap_ = agA + (size_t)(T) * 32;                      \
    const unsigned short* bp_ = bgB + (size_t)(T) * 32;                      \
    gl_lds16(ap_,           &As[(SB) * 4096 + lA0]);                         \
    gl_lds16(ap_ + 64 * DM, &As[(SB) * 4096 + lA0 + 512]);                   \
    gl_lds16(bp_,           &Bs[(SB) * 4096 + lB0]);                         \
    gl_lds16(bp_ + 64 * DM, &Bs[(SB) * 4096 + lB0 + 512]);                   \
  } while (0)

#define COMPUTE(CB) do {                                                     \
    bf16x8 af_[4], bq_[4];                                                   \
    _Pragma("unroll")                                                        \
    for (int mi = 0; mi < 4; ++mi)                                           \
      af_[mi] = *(const bf16x8*)&As[(CB) * 4096 + raA + mi * 128];           \
    _Pragma("unroll")                                                        \
    for (int ni = 0; ni < 4; ++ni)                                           \
      bq_[ni] = *(const bf16x8*)&Bs[(CB) * 4096 + raB + ni * 128];           \
    __builtin_amdgcn_s_setprio(1);                                           \
    _Pragma("unroll")                                                        \
    for (int mi = 0; mi < 4; ++mi)                                           \
      _Pragma("unroll")                                                      \
      for (int ni = 0; ni < 4; ++ni)                                         \
        acc[mi][ni] = __builtin_amdgcn_mfma_f32_16x16x32_bf16(af_[mi], bq_[ni], acc[mi][ni], 0, 0, 0); \
    __builtin_amdgcn_s_setprio(0);                                           \
  } while (0)

#define SUBSTEP(T, SB, CB) do {                                              \
    asm volatile("s_waitcnt vmcnt(4)" ::: "memory");                         \
    __builtin_amdgcn_s_barrier();                                            \
    FENCE();                                                                 \
    STAGE4((T), (SB));                                                       \
    COMPUTE(CB);                                                             \
    FENCE();                                                                 \
  } while (0)

  STAGE4(0, 0);
  STAGE4(1, 1);

  for (int t = 0; t < 30; t += 3) {
    SUBSTEP(t + 2, 2, 0);
    SUBSTEP(t + 3, 0, 1);
    SUBSTEP(t + 4, 1, 2);
  }
  asm volatile("s_waitcnt vmcnt(4)" ::: "memory");
  __builtin_amdgcn_s_barrier();
  FENCE();
  COMPUTE(0);
  asm volatile("s_waitcnt vmcnt(0)" ::: "memory");
  __builtin_amdgcn_s_barrier();
  FENCE();
  COMPUTE(1);

#undef SUBSTEP
#undef COMPUTE
#undef STAGE4

#pragma unroll
  for (int mi = 0; mi < 4; ++mi) {
#pragma unroll
    for (int reg = 0; reg < 4; ++reg) {
      const int m = m0 + wr * 64 + mi * 16 + quad * 4 + reg;
#pragma unroll
      for (int ni = 0; ni < 4; ++ni) {
        const int e = n0 + wc * 64 + ni * 16 + l15;
        outF[(size_t)m * DM + e] = acc[mi][ni][reg];
      }
    }
  }
}

// ---------------------------------------------------------------------------
// MFMA flash attention on 32x32x16, swapped QK^T, in-register softmax+P.
// R22-verified: LDS double-buffered K/V + T14 async-stage; ONE barrier/jt.
// ---------------------------------------------------------------------------
__global__ __launch_bounds__(256, 4) void attn_mfma(const unsigned short* __restrict__ Q,
                                                    const unsigned short* __restrict__ K,
                                                    const unsigned short* __restrict__ V,
                                                    unsigned short* __restrict__ O) {
  __shared__ unsigned short Ks[2][64][72];
  __shared__ unsigned short Vt[2][64][72];
  const int bh = blockIdx.x;                 // 0..63
  const int bx = 15 - (int)blockIdx.y;       // heavy q-blocks dispatched first
  const int tid = threadIdx.x;
  const int w = tid >> 6, lane = tid & 63;
  const int l31 = lane & 31, hi = lane >> 5;
  const size_t base = (size_t)bh * S_LEN * HD;
  const int b = bh >> 4, h = bh & 15;
  const int wq0 = bx * 128 + w * 32;
  const int diag_jt = 2 * bx + (w >> 1);     // wave's last (and partial) tile
  const int jt_blk = 2 * bx + 1;             // block's last tile
  const int kr0 = tid >> 3, kc0 = (tid & 7) * 8;
  const int vs = (tid & 31) * 2, vh = (tid >> 5) * 8;

  // Q fragments (B-operand): lane (hi,q=l31) holds d = ds*16 + hi*8 + e
  bf16x8 qb[4];
#pragma unroll
  for (int ds = 0; ds < 4; ++ds)
    qb[ds] = *(const bf16x8*)(Q + base + (size_t)(wq0 + l31) * HD + ds * 16 + hi * 8);

  f32x16 o0, o1;
#pragma unroll
  for (int r = 0; r < 16; ++r) { o0[r] = 0.f; o1[r] = 0.f; }
  float l_acc = 0.f;

  // prologue: tile 0 -> regs -> buf 0
  uint4 kA, kB, vA, vB;
  {
    const unsigned short* kgp = K + base;
    const unsigned short* vgp = V + base;
    kA = *(const uint4*)(kgp + kr0 * HD + kc0);
    kB = *(const uint4*)(kgp + (kr0 + 32) * HD + kc0);
    vA = *(const uint4*)(vgp + (size_t)vs * HD + vh);
    vB = *(const uint4*)(vgp + (size_t)(vs + 1) * HD + vh);
  }
  {
    *(uint4*)&Ks[0][kr0][kc0]      = kA;
    *(uint4*)&Ks[0][kr0 + 32][kc0] = kB;
    const unsigned int* a0 = (const unsigned int*)&vA;
    const unsigned int* a1 = (const unsigned int*)&vB;
#pragma unroll
    for (int j = 0; j < 4; ++j) {
      *(unsigned int*)&Vt[0][vh + 2 * j][vs]     = __builtin_amdgcn_perm(a1[j], a0[j], 0x05040100u);
      *(unsigned int*)&Vt[0][vh + 2 * j + 1][vs] = __builtin_amdgcn_perm(a1[j], a0[j], 0x07060302u);
    }
  }

  for (int jt = 0; jt <= jt_blk; ++jt) {
    const int cb = jt & 1;
    __syncthreads();   // buf[cb] writes visible; all reads of buf[cb^1] done

    if (jt < jt_blk) {
      const unsigned short* kgp = K + base + (size_t)(jt + 1) * 64 * HD;
      const unsigned short* vgp = V + base + (size_t)(jt + 1) * 64 * HD;
      kA = *(const uint4*)(kgp + kr0 * HD + kc0);
      kB = *(const uint4*)(kgp + (kr0 + 32) * HD + kc0);
      vA = *(const uint4*)(vgp + (size_t)vs * HD + vh);
      vB = *(const uint4*)(vgp + (size_t)(vs + 1) * HD + vh);
    }

    if (jt <= diag_jt) {                      // wave-uniform
      const bool diag = (jt == diag_jt);
      for (int kb = 0; kb < 2; ++kb) {
        const bool kb_zero = diag && ((w & 1) == 0) && (kb == 1);
        const bool kb_part = diag && (kb == (w & 1));
        if (kb_zero) continue;                // wave-uniform; no contribution

        f32x16 sa;
#pragma unroll
        for (int r = 0; r < 16; ++r) sa[r] = 0.f;
        __builtin_amdgcn_s_setprio(1);
#pragma unroll
        for (int ds = 0; ds < 4; ++ds) {
          bf16x8 kf = *(const bf16x8*)&Ks[cb][kb * 32 + l31][ds * 16 + hi * 8];
          sa = __builtin_amdgcn_mfma_f32_32x32x16_bf16(kf, qb[ds], sa, 0, 0, 0);
        }
        __builtin_amdgcn_s_setprio(0);

        float p[16];
        if (kb_part) {
#pragma unroll
          for (int r = 0; r < 16; ++r) {
            const int krel = (r & 3) + 8 * (r >> 2) + 4 * hi;
            p[r] = __expf((l31 >= krel) ? sa[r] : -1.0e30f);
          }
        } else {
#pragma unroll
          for (int r = 0; r < 16; ++r) p[r] = __expf(sa[r]);
        }
        l_acc += (((p[0] + p[1]) + (p[2] + p[3])) + ((p[4] + p[5]) + (p[6] + p[7])))
               + (((p[8] + p[9]) + (p[10] + p[11])) + ((p[12] + p[13]) + (p[14] + p[15])));

        unsigned int pk[8], sk[8];
#pragma unroll
        for (int g = 0; g < 4; ++g) {
          pk[2 * g]     = __builtin_amdgcn_perm(__float_as_uint(p[4 * g + 1]), __float_as_uint(p[4 * g]),     0x07060302u);
          pk[2 * g + 1] = __builtin_amdgcn_perm(__float_as_uint(p[4 * g + 3]), __float_as_uint(p[4 * g + 2]), 0x07060302u);
        }
#pragma unroll
        for (int i = 0; i < 8; ++i) sk[i] = (unsigned int)__shfl_xor((int)pk[i], 32);

#pragma unroll
        for (int sl = 0; sl < 2; ++sl) {
          const int g0 = 2 * sl, g1 = 2 * sl + 1;
          union { unsigned int u[4]; bf16x8 v; } fa;
          fa.u[0] = hi ? sk[2 * g1]     : pk[2 * g0];
          fa.u[1] = hi ? sk[2 * g1 + 1] : pk[2 * g0 + 1];
          fa.u[2] = hi ? pk[2 * g1]     : sk[2 * g0];
          fa.u[3] = hi ? pk[2 * g1 + 1] : sk[2 * g0 + 1];
          const int s = kb * 2 + sl;
          bf16x8 v0 = *(const bf16x8*)&Vt[cb][l31][s * 16 + hi * 8];
          bf16x8 v1 = *(const bf16x8*)&Vt[cb][32 + l31][s * 16 + hi * 8];
          __builtin_amdgcn_s_setprio(1);
          o0 = __builtin_amdgcn_mfma_f32_32x32x16_bf16(fa.v, v0, o0, 0, 0, 0);
          o1 = __builtin_amdgcn_mfma_f32_32x32x16_bf16(fa.v, v1, o1, 0, 0, 0);
          __builtin_amdgcn_s_setprio(0);
        }
      }
    }

    if (jt < jt_blk) {
      const int nb = cb ^ 1;
      *(uint4*)&Ks[nb][kr0][kc0]      = kA;
      *(uint4*)&Ks[nb][kr0 + 32][kc0] = kB;
      const unsigned int* a0 = (const unsigned int*)&vA;
      const unsigned int* a1 = (const unsigned int*)&vB;
#pragma unroll
      for (int j = 0; j < 4; ++j) {
        *(unsigned int*)&Vt[nb][vh + 2 * j][vs]     = __builtin_amdgcn_perm(a1[j], a0[j], 0x05040100u);
        *(unsigned int*)&Vt[nb][vh + 2 * j + 1][vs] = __builtin_amdgcn_perm(a1[j], a0[j], 0x07060302u);
      }
    }
  }

  // epilogue: l total (xor32 joins the two k-halves), scale + write O
  const float lf = l_acc + __shfl_xor(l_acc, 32);
  const float inv = 1.0f / lf;
#pragma unroll
  for (int r = 0; r < 16; ++r) {
    const int qrel = (r & 3) + 8 * (r >> 2) + 4 * hi;
    const float invr = __shfl(inv, qrel);    // lane qrel holds l for q=wq0+qrel
    const size_t orow = (size_t)(b * S_LEN + wq0 + qrel) * DM + h * HD;
    O[orow + l31]      = f2bf(o0[r] * invr);
    O[orow + 32 + l31] = f2bf(o1[r] * invr);
  }
}

extern "C" void kernel_launch(void* const* d_in, const int* in_sizes, int n_in,
                              void* d_out, int out_size, void* d_ws, size_t ws_size,
                              hipStream_t stream) {
  const float* x  = (const float*)d_in[0];  // fp32 [4,2048,1024]
  const float* wq = (const float*)d_in[1];  // fp32 [1024,1024]
  const float* wk = (const float*)d_in[2];
  const float* wv = (const float*)d_in[3];
  const float* wo = (const float*)d_in[4];

  unsigned short* Qb = (unsigned short*)d_ws;                 // 16 MB
  unsigned short* Kb = Qb + (size_t)M_ROWS * DM;              // 16 MB (Qb+z*16M)
  unsigned short* Vb = Kb + (size_t)M_ROWS * DM;              // 16 MB
  unsigned short* Ob = Vb + (size_t)M_ROWS * DM;              // 16 MB
  (void)Kb; (void)Vb;

  // bf16 weight stash inside d_out (32 MB fp32 buffer; dead until final GEMM)
  unsigned short* Wstash = (unsigned short*)d_out;            // [3072][1024] bf16

  dim3 bb(256);
  dim3 gb(512);

  hipLaunchKernelGGL(cvt_w3, dim3(3 * (DM * DM) / 2048), bb, 0, stream, wq, wk, wv, Wstash);
  // fused QKV as single GEMM from fp32 X: M=8192, N=3072 (z = e>>10 slab)
  hipLaunchKernelGGL(gemm_qkv, dim3(M_ROWS / 256, 3 * DM / 128), gb, 0, stream,
                     x, Wstash, Qb);
  hipLaunchKernelGGL(attn_mfma, dim3(64, 16), bb, 0, stream, Qb, Qb + (size_t)M_ROWS * DM,
                     Qb + 2 * (size_t)M_ROWS * DM, Ob);
  // wo -> bf16 into Qb (free after attention); then final projection
  hipLaunchKernelGGL(cvt_bf16, dim3((DM * DM) / 2048), bb, 0, stream, wo, Qb);
  hipLaunchKernelGGL(gemm_out, dim3(M_ROWS / 128, DM / 128), bb, 0, stream,
                     Ob, Qb, (float*)d_out);
}

// Round 15
// 194.495 us; speedup vs baseline: 1.2012x; 1.2012x over previous
//
#include <hip/hip_runtime.h>
#include <hip/hip_bf16.h>
#include <math.h>

// Problem: MultiHeadSelfAttention  B=4, S=2048, D=1024, H=16, Hd=64
// fp32 in / fp32 out. bf16 scratch, fp32 accumulation.
// Round 24 (= R22 exact revert; R23's fused fp32-A cvt falsified:
// 93->153us, reg-staged ds_write + lgkm drain re-created the alignment
// stall gl_lds avoids, and fp32 X doubled FETCH):
//  - QKV gemm: R16 exact (ring-3 counted-vmcnt, 256x128, 8 waves,
//    1 barrier/K-step; 93.5us verified 4x).
//  - attn: R22-verified (T14 async-stage + LDS dbuf, one barrier/jt).
//  - final gemm: R18/R21-verified 128^2/4w.
// ws: Qb@0, Kb@16M, Vb@32M, Xb/Ob@48M (aliased). Wstash in d_out (dead
// until final GEMM); wo converted into Qb after attention frees it.

#define S_LEN 2048
#define DM    1024
#define NH    16
#define HD    64
#define M_ROWS 8192   // B * S

typedef __attribute__((ext_vector_type(8))) short bf16x8;
typedef __attribute__((ext_vector_type(4))) float f32x4;
typedef __attribute__((ext_vector_type(16))) float f32x16;

__device__ __forceinline__ float bf2f(unsigned short u) {
  union { unsigned int i; float f; } c; c.i = ((unsigned int)u) << 16; return c.f;
}
__device__ __forceinline__ unsigned short f2bf(float f) {
  unsigned int x = __float_as_uint(f);
  if ((x & 0x7fffffffu) > 0x7f800000u) return (unsigned short)0x7fc0u;  // NaN
  return (unsigned short)((x + 0x7fffu + ((x >> 16) & 1u)) >> 16);      // RNE
}
// async global->LDS, 16 B per lane; lds dest must be wave-uniform
__device__ __forceinline__ void gl_lds16(const unsigned short* g, unsigned short* l) {
  __builtin_amdgcn_global_load_lds(
      (const __attribute__((address_space(1))) unsigned int*)g,
      (__attribute__((address_space(3))) unsigned int*)l, 16, 0, 0);
}

#define FENCE() asm volatile("" ::: "memory")

// ---------------------------------------------------------------------------
// fp32 -> bf16 bulk convert (8 elems/thread)
// ---------------------------------------------------------------------------
__global__ __launch_bounds__(256) void cvt_bf16(const float* __restrict__ in,
                                                unsigned short* __restrict__ out) {
  const int i = blockIdx.x * 256 + threadIdx.x;
  float4 a = ((const float4*)in)[2 * i];
  float4 b = ((const float4*)in)[2 * i + 1];
  ushort4 r0, r1;
  r0.x = f2bf(a.x); r0.y = f2bf(a.y); r0.z = f2bf(a.z); r0.w = f2bf(a.w);
  r1.x = f2bf(b.x); r1.y = f2bf(b.y); r1.z = f2bf(b.z); r1.w = f2bf(b.w);
  ((ushort4*)out)[2 * i] = r0;
  ((ushort4*)out)[2 * i + 1] = r1;
}

// convert wq,wk,wv (1M fp32 each) into one contiguous bf16 stash [3072][1024]
__global__ __launch_bounds__(256) void cvt_w3(const float* __restrict__ w0,
                                              const float* __restrict__ w1,
                                              const float* __restrict__ w2,
                                              unsigned short* __restrict__ out) {
  const int idx = blockIdx.x;                 // 0..1535
  const int which = idx >> 9;
  const float* src = (which == 0) ? w0 : (which == 1) ? w1 : w2;
  unsigned short* dst = out + (size_t)which * (DM * DM);
  const int i = (idx & 511) * 256 + threadIdx.x;
  float4 a = ((const float4*)src)[2 * i];
  float4 b = ((const float4*)src)[2 * i + 1];
  ushort4 r0, r1;
  r0.x = f2bf(a.x); r0.y = f2bf(a.y); r0.z = f2bf(a.z); r0.w = f2bf(a.w);
  r1.x = f2bf(b.x); r1.y = f2bf(b.y); r1.z = f2bf(b.z); r1.w = f2bf(b.w);
  ((ushort4*)dst)[2 * i] = r0;
  ((ushort4*)dst)[2 * i + 1] = r1;
}

// ---------------------------------------------------------------------------
// QKV GEMM (R16 exact): counted-vmcnt ring-3, 256x128, 8 waves, 1 bar/K-step.
// C[m,e] = sum_d A[m,d] * Wall[e,d].  bf16 out, z-slab scatter.
// ---------------------------------------------------------------------------
__global__ __launch_bounds__(512, 4) void gemm_qkv(const unsigned short* __restrict__ A,
                                                   const unsigned short* __restrict__ Wall,
                                                   unsigned short* __restrict__ outB) {
  __shared__ __align__(16) unsigned short As[3 * 8192];  // [buf][kgrp4][256][8]
  __shared__ __align__(16) unsigned short Bs[3 * 4096];  // [buf][kgrp4][128][8]
  const int m0 = blockIdx.x * 256;
  const int n0 = blockIdx.y * 128;
  const int tid = threadIdx.x;
  const int lane = tid & 63, w = tid >> 6;
  const int quad = lane >> 4, l15 = lane & 15;
  const int wrow = w >> 1, wcol = w & 1;    // compute mapping: 4M x 2N waves

  const int skg = w & 3, srq = w >> 2;
  const unsigned short* agA = A    + (size_t)(m0 + srq * 64 + lane) * DM + skg * 8;
  const unsigned short* bgB = Wall + (size_t)(n0 + srq * 64 + lane) * DM + skg * 8;
  const int lA0 = skg * 2048 + srq * 512;   // wave-uniform LDS elem offsets
  const int lA1 = lA0 + 1024;               // rows +128
  const int lB  = skg * 1024 + srq * 512;
  const int raA = quad * 2048 + (wrow * 64 + l15) * 8;  // frag-read bases
  const int raB = quad * 1024 + (wcol * 64 + l15) * 8;

  f32x4 acc[4][4];
#pragma unroll
  for (int i = 0; i < 4; ++i)
#pragma unroll
    for (int j = 0; j < 4; ++j) { acc[i][j].x = 0.f; acc[i][j].y = 0.f; acc[i][j].z = 0.f; acc[i][j].w = 0.f; }

#define STAGE3(T, SB) do {                                                   \
    const unsigned short* ap_ = agA + (size_t)(T) * 32;                      \
    gl_lds16(ap_,          &As[(SB) * 8192 + lA0]);                          \
    gl_lds16(ap_ + 131072, &As[(SB) * 8192 + lA1]);                          \
    gl_lds16(bgB + (size_t)(T) * 32, &Bs[(SB) * 4096 + lB]);                 \
  } while (0)

#define COMPUTE(CB) do {                                                     \
    bf16x8 af_[4], bq_[4];                                                   \
    _Pragma("unroll")                                                        \
    for (int mi = 0; mi < 4; ++mi)                                           \
      af_[mi] = *(const bf16x8*)&As[(CB) * 8192 + raA + mi * 128];           \
    _Pragma("unroll")                                                        \
    for (int ni = 0; ni < 4; ++ni)                                           \
      bq_[ni] = *(const bf16x8*)&Bs[(CB) * 4096 + raB + ni * 128];           \
    __builtin_amdgcn_s_setprio(1);                                           \
    _Pragma("unroll")                                                        \
    for (int mi = 0; mi < 4; ++mi)                                           \
      _Pragma("unroll")                                                      \
      for (int ni = 0; ni < 4; ++ni)                                         \
        acc[mi][ni] = __builtin_amdgcn_mfma_f32_16x16x32_bf16(af_[mi], bq_[ni], acc[mi][ni], 0, 0, 0); \
    __builtin_amdgcn_s_setprio(0);                                           \
  } while (0)

#define SUBSTEP(T, SB, CB) do {                                              \
    asm volatile("s_waitcnt vmcnt(3)" ::: "memory");                         \
    __builtin_amdgcn_s_barrier();                                            \
    FENCE();                                                                 \
    STAGE3((T), (SB));                                                       \
    COMPUTE(CB);                                                             \
    FENCE();                                                                 \
  } while (0)

  STAGE3(0, 0);
  STAGE3(1, 1);

  for (int t = 0; t < 30; t += 3) {
    SUBSTEP(t + 2, 2, 0);
    SUBSTEP(t + 3, 0, 1);
    SUBSTEP(t + 4, 1, 2);
  }
  asm volatile("s_waitcnt vmcnt(3)" ::: "memory");
  __builtin_amdgcn_s_barrier();
  FENCE();
  COMPUTE(0);
  asm volatile("s_waitcnt vmcnt(0)" ::: "memory");
  __builtin_amdgcn_s_barrier();
  FENCE();
  COMPUTE(1);

#undef SUBSTEP
#undef COMPUTE
#undef STAGE3

  const float oscale = (n0 < 1024) ? 0.125f : 1.0f;
#pragma unroll
  for (int mi = 0; mi < 4; ++mi) {
#pragma unroll
    for (int reg = 0; reg < 4; ++reg) {
      const int m = m0 + wrow * 64 + mi * 16 + quad * 4 + reg;
#pragma unroll
      for (int ni = 0; ni < 4; ++ni) {
        const int e = n0 + wcol * 64 + ni * 16 + l15;
        const float v = acc[mi][ni][reg];
        const int z = e >> 10;                   // 0:Q 1:K 2:V
        const int e10 = e & 1023;
        const int b = m >> 11, s = m & (S_LEN - 1);
        const int h = e10 >> 6, hd = e10 & 63;
        outB[(size_t)z * (M_ROWS * DM) +
             (((size_t)(b * NH + h)) * S_LEN + s) * HD + hd] = f2bf(v * oscale);
      }
    }
  }
}

// ---------------------------------------------------------------------------
// Final GEMM (R18/R21-verified 128^2/4w): counted-vmcnt ring-3, fp32 out.
// ---------------------------------------------------------------------------
__global__ __launch_bounds__(256, 2) void gemm_out(const unsigned short* __restrict__ A,
                                                   const unsigned short* __restrict__ Wb,
                                                   float* __restrict__ outF) {
  __shared__ __align__(16) unsigned short As[3 * 4096];  // [buf][kgrp4][128][8]
  __shared__ __align__(16) unsigned short Bs[3 * 4096];
  const int m0 = blockIdx.x * 128;
  const int n0 = blockIdx.y * 128;
  const int tid = threadIdx.x;
  const int lane = tid & 63, w = tid >> 6;   // 4 waves
  const int quad = lane >> 4, l15 = lane & 15;
  const int wr = w >> 1, wc = w & 1;         // compute mapping: 2M x 2N waves

  const unsigned short* agA = A  + (size_t)(m0 + lane) * DM + w * 8;
  const unsigned short* bgB = Wb + (size_t)(n0 + lane) * DM + w * 8;
  const int lA0 = w * 1024;                  // elem base (kgrp=w, rows 0..63)
  const int lB0 = w * 1024;
  const int raA = quad * 1024 + (wr * 64 + l15) * 8;  // frag-read bases
  const int raB = quad * 1024 + (wc * 64 + l15) * 8;

  f32x4 acc[4][4];
#pragma unroll
  for (int i = 0; i < 4; ++i)
#pragma unroll
    for (int j = 0; j < 4; ++j) { acc[i][j].x = 0.f; acc[i][j].y = 0.f; acc[i][j].z = 0.f; acc[i][j].w = 0.f; }

#define STAGE4(T, SB) do {                                                   \
    const unsigned short* ap_ = agA + (size_t)(T) * 32;                      \
    const unsigned short* bp_ = bgB + (size_t)(T) * 32;                      \
    gl_lds16(ap_,           &As[(SB) * 4096 + lA0]);                         \
    gl_lds16(ap_ + 64 * DM, &As[(SB) * 4096 + lA0 + 512]);                   \
    gl_lds16(bp_,           &Bs[(SB) * 4096 + lB0]);                         \
    gl_lds16(bp_ + 64 * DM, &Bs[(SB) * 4096 + lB0 + 512]);                   \
  } while (0)

#define COMPUTE(CB) do {                                                     \
    bf16x8 af_[4], bq_[4];                                                   \
    _Pragma("unroll")                                                        \
    for (int mi = 0; mi < 4; ++mi)                                           \
      af_[mi] = *(const bf16x8*)&As[(CB) * 4096 + raA + mi * 128];           \
    _Pragma("unroll")                                                        \
    for (int ni = 0; ni < 4; ++ni)                                           \
      bq_[ni] = *(const bf16x8*)&Bs[(CB) * 4096 + raB + ni * 128];           \
    __builtin_amdgcn_s_setprio(1);                                           \
    _Pragma("unroll")                                                        \
    for (int mi = 0; mi < 4; ++mi)                                           \
      _Pragma("unroll")                                                      \
      for (int ni = 0; ni < 4; ++ni)                                         \
        acc[mi][ni] = __builtin_amdgcn_mfma_f32_16x16x32_bf16(af_[mi], bq_[ni], acc[mi][ni], 0, 0, 0); \
    __builtin_amdgcn_s_setprio(0);                                           \
  } while (0)

#define SUBSTEP(T, SB, CB) do {                                              \
    asm volatile("s_waitcnt vmcnt(4)" ::: "memory");                         \
    __builtin_amdgcn_s_barrier();                                            \
    FENCE();                                                                 \
    STAGE4((T), (SB));                                                       \
    COMPUTE(CB);                                                             \
    FENCE();                                                                 \
  } while (0)

  STAGE4(0, 0);
  STAGE4(1, 1);

  for (int t = 0; t < 30; t += 3) {
    SUBSTEP(t + 2, 2, 0);
    SUBSTEP(t + 3, 0, 1);
    SUBSTEP(t + 4, 1, 2);
  }
  asm volatile("s_waitcnt vmcnt(4)" ::: "memory");
  __builtin_amdgcn_s_barrier();
  FENCE();
  COMPUTE(0);
  asm volatile("s_waitcnt vmcnt(0)" ::: "memory");
  __builtin_amdgcn_s_barrier();
  FENCE();
  COMPUTE(1);

#undef SUBSTEP
#undef COMPUTE
#undef STAGE4

#pragma unroll
  for (int mi = 0; mi < 4; ++mi) {
#pragma unroll
    for (int reg = 0; reg < 4; ++reg) {
      const int m = m0 + wr * 64 + mi * 16 + quad * 4 + reg;
#pragma unroll
      for (int ni = 0; ni < 4; ++ni) {
        const int e = n0 + wc * 64 + ni * 16 + l15;
        outF[(size_t)m * DM + e] = acc[mi][ni][reg];
      }
    }
  }
}

// ---------------------------------------------------------------------------
// MFMA flash attention on 32x32x16, swapped QK^T, in-register softmax+P.
// R22-verified: LDS double-buffered K/V + T14 async-stage; ONE barrier/jt.
// ---------------------------------------------------------------------------
__global__ __launch_bounds__(256, 4) void attn_mfma(const unsigned short* __restrict__ Q,
                                                    const unsigned short* __restrict__ K,
                                                    const unsigned short* __restrict__ V,
                                                    unsigned short* __restrict__ O) {
  __shared__ unsigned short Ks[2][64][72];
  __shared__ unsigned short Vt[2][64][72];
  const int bh = blockIdx.x;                 // 0..63
  const int bx = 15 - (int)blockIdx.y;       // heavy q-blocks dispatched first
  const int tid = threadIdx.x;
  const int w = tid >> 6, lane = tid & 63;
  const int l31 = lane & 31, hi = lane >> 5;
  const size_t base = (size_t)bh * S_LEN * HD;
  const int b = bh >> 4, h = bh & 15;
  const int wq0 = bx * 128 + w * 32;
  const int diag_jt = 2 * bx + (w >> 1);     // wave's last (and partial) tile
  const int jt_blk = 2 * bx + 1;             // block's last tile
  const int kr0 = tid >> 3, kc0 = (tid & 7) * 8;
  const int vs = (tid & 31) * 2, vh = (tid >> 5) * 8;

  // Q fragments (B-operand): lane (hi,q=l31) holds d = ds*16 + hi*8 + e
  bf16x8 qb[4];
#pragma unroll
  for (int ds = 0; ds < 4; ++ds)
    qb[ds] = *(const bf16x8*)(Q + base + (size_t)(wq0 + l31) * HD + ds * 16 + hi * 8);

  f32x16 o0, o1;
#pragma unroll
  for (int r = 0; r < 16; ++r) { o0[r] = 0.f; o1[r] = 0.f; }
  float l_acc = 0.f;

  // prologue: tile 0 -> regs -> buf 0
  uint4 kA, kB, vA, vB;
  {
    const unsigned short* kgp = K + base;
    const unsigned short* vgp = V + base;
    kA = *(const uint4*)(kgp + kr0 * HD + kc0);
    kB = *(const uint4*)(kgp + (kr0 + 32) * HD + kc0);
    vA = *(const uint4*)(vgp + (size_t)vs * HD + vh);
    vB = *(const uint4*)(vgp + (size_t)(vs + 1) * HD + vh);
  }
  {
    *(uint4*)&Ks[0][kr0][kc0]      = kA;
    *(uint4*)&Ks[0][kr0 + 32][kc0] = kB;
    const unsigned int* a0 = (const unsigned int*)&vA;
    const unsigned int* a1 = (const unsigned int*)&vB;
#pragma unroll
    for (int j = 0; j < 4; ++j) {
      *(unsigned int*)&Vt[0][vh + 2 * j][vs]     = __builtin_amdgcn_perm(a1[j], a0[j], 0x05040100u);
      *(unsigned int*)&Vt[0][vh + 2 * j + 1][vs] = __builtin_amdgcn_perm(a1[j], a0[j], 0x07060302u);
    }
  }

  for (int jt = 0; jt <= jt_blk; ++jt) {
    const int cb = jt & 1;
    __syncthreads();   // buf[cb] writes visible; all reads of buf[cb^1] done

    if (jt < jt_blk) {
      const unsigned short* kgp = K + base + (size_t)(jt + 1) * 64 * HD;
      const unsigned short* vgp = V + base + (size_t)(jt + 1) * 64 * HD;
      kA = *(const uint4*)(kgp + kr0 * HD + kc0);
      kB = *(const uint4*)(kgp + (kr0 + 32) * HD + kc0);
      vA = *(const uint4*)(vgp + (size_t)vs * HD + vh);
      vB = *(const uint4*)(vgp + (size_t)(vs + 1) * HD + vh);
    }

    if (jt <= diag_jt) {                      // wave-uniform
      const bool diag = (jt == diag_jt);
      for (int kb = 0; kb < 2; ++kb) {
        const bool kb_zero = diag && ((w & 1) == 0) && (kb == 1);
        const bool kb_part = diag && (kb == (w & 1));
        if (kb_zero) continue;                // wave-uniform; no contribution

        f32x16 sa;
#pragma unroll
        for (int r = 0; r < 16; ++r) sa[r] = 0.f;
        __builtin_amdgcn_s_setprio(1);
#pragma unroll
        for (int ds = 0; ds < 4; ++ds) {
          bf16x8 kf = *(const bf16x8*)&Ks[cb][kb * 32 + l31][ds * 16 + hi * 8];
          sa = __builtin_amdgcn_mfma_f32_32x32x16_bf16(kf, qb[ds], sa, 0, 0, 0);
        }
        __builtin_amdgcn_s_setprio(0);

        float p[16];
        if (kb_part) {
#pragma unroll
          for (int r = 0; r < 16; ++r) {
            const int krel = (r & 3) + 8 * (r >> 2) + 4 * hi;
            p[r] = __expf((l31 >= krel) ? sa[r] : -1.0e30f);
          }
        } else {
#pragma unroll
          for (int r = 0; r < 16; ++r) p[r] = __expf(sa[r]);
        }
        l_acc += (((p[0] + p[1]) + (p[2] + p[3])) + ((p[4] + p[5]) + (p[6] + p[7])))
               + (((p[8] + p[9]) + (p[10] + p[11])) + ((p[12] + p[13]) + (p[14] + p[15])));

        unsigned int pk[8], sk[8];
#pragma unroll
        for (int g = 0; g < 4; ++g) {
          pk[2 * g]     = __builtin_amdgcn_perm(__float_as_uint(p[4 * g + 1]), __float_as_uint(p[4 * g]),     0x07060302u);
          pk[2 * g + 1] = __builtin_amdgcn_perm(__float_as_uint(p[4 * g + 3]), __float_as_uint(p[4 * g + 2]), 0x07060302u);
        }
#pragma unroll
        for (int i = 0; i < 8; ++i) sk[i] = (unsigned int)__shfl_xor((int)pk[i], 32);

#pragma unroll
        for (int sl = 0; sl < 2; ++sl) {
          const int g0 = 2 * sl, g1 = 2 * sl + 1;
          union { unsigned int u[4]; bf16x8 v; } fa;
          fa.u[0] = hi ? sk[2 * g1]     : pk[2 * g0];
          fa.u[1] = hi ? sk[2 * g1 + 1] : pk[2 * g0 + 1];
          fa.u[2] = hi ? pk[2 * g1]     : sk[2 * g0];
          fa.u[3] = hi ? pk[2 * g1 + 1] : sk[2 * g0 + 1];
          const int s = kb * 2 + sl;
          bf16x8 v0 = *(const bf16x8*)&Vt[cb][l31][s * 16 + hi * 8];
          bf16x8 v1 = *(const bf16x8*)&Vt[cb][32 + l31][s * 16 + hi * 8];
          __builtin_amdgcn_s_setprio(1);
          o0 = __builtin_amdgcn_mfma_f32_32x32x16_bf16(fa.v, v0, o0, 0, 0, 0);
          o1 = __builtin_amdgcn_mfma_f32_32x32x16_bf16(fa.v, v1, o1, 0, 0, 0);
          __builtin_amdgcn_s_setprio(0);
        }
      }
    }

    if (jt < jt_blk) {
      const int nb = cb ^ 1;
      *(uint4*)&Ks[nb][kr0][kc0]      = kA;
      *(uint4*)&Ks[nb][kr0 + 32][kc0] = kB;
      const unsigned int* a0 = (const unsigned int*)&vA;
      const unsigned int* a1 = (const unsigned int*)&vB;
#pragma unroll
      for (int j = 0; j < 4; ++j) {
        *(unsigned int*)&Vt[nb][vh + 2 * j][vs]     = __builtin_amdgcn_perm(a1[j], a0[j], 0x05040100u);
        *(unsigned int*)&Vt[nb][vh + 2 * j + 1][vs] = __builtin_amdgcn_perm(a1[j], a0[j], 0x07060302u);
      }
    }
  }

  // epilogue: l total (xor32 joins the two k-halves), scale + write O
  const float lf = l_acc + __shfl_xor(l_acc, 32);
  const float inv = 1.0f / lf;
#pragma unroll
  for (int r = 0; r < 16; ++r) {
    const int qrel = (r & 3) + 8 * (r >> 2) + 4 * hi;
    const float invr = __shfl(inv, qrel);    // lane qrel holds l for q=wq0+qrel
    const size_t orow = (size_t)(b * S_LEN + wq0 + qrel) * DM + h * HD;
    O[orow + l31]      = f2bf(o0[r] * invr);
    O[orow + 32 + l31] = f2bf(o1[r] * invr);
  }
}

extern "C" void kernel_launch(void* const* d_in, const int* in_sizes, int n_in,
                              void* d_out, int out_size, void* d_ws, size_t ws_size,
                              hipStream_t stream) {
  const float* x  = (const float*)d_in[0];  // fp32 [4,2048,1024]
  const float* wq = (const float*)d_in[1];  // fp32 [1024,1024]
  const float* wk = (const float*)d_in[2];
  const float* wv = (const float*)d_in[3];
  const float* wo = (const float*)d_in[4];

  unsigned short* Qb = (unsigned short*)d_ws;                 // 16 MB
  unsigned short* Kb = Qb + (size_t)M_ROWS * DM;              // 16 MB (Qb+z*16M)
  unsigned short* Vb = Kb + (size_t)M_ROWS * DM;              // 16 MB
  unsigned short* Xb = Vb + (size_t)M_ROWS * DM;              // 16 MB (alias Ob)
  unsigned short* Ob = Xb;
  (void)Kb; (void)Vb;

  // bf16 weight stash inside d_out (32 MB fp32 buffer; dead until final GEMM)
  unsigned short* Wstash = (unsigned short*)d_out;            // [3072][1024] bf16

  dim3 bb(256);
  dim3 gb(512);

  hipLaunchKernelGGL(cvt_bf16, dim3((M_ROWS * DM) / 2048), bb, 0, stream, x, Xb);
  hipLaunchKernelGGL(cvt_w3, dim3(3 * (DM * DM) / 2048), bb, 0, stream, wq, wk, wv, Wstash);
  // fused QKV as single GEMM: M=8192, N=3072 (z = e>>10 selects output slab)
  hipLaunchKernelGGL(gemm_qkv, dim3(M_ROWS / 256, 3 * DM / 128), gb, 0, stream,
                     Xb, Wstash, Qb);
  hipLaunchKernelGGL(attn_mfma, dim3(64, 16), bb, 0, stream, Qb, Qb + (size_t)M_ROWS * DM,
                     Qb + 2 * (size_t)M_ROWS * DM, Ob);
  // wo -> bf16 into Qb (free after attention); then final projection
  hipLaunchKernelGGL(cvt_bf16, dim3((DM * DM) / 2048), bb, 0, stream, wo, Qb);
  hipLaunchKernelGGL(gemm_out, dim3(M_ROWS / 128, DM / 128), bb, 0, stream,
                     Ob, Qb, (float*)d_out);
}

// Round 16
// 192.594 us; speedup vs baseline: 1.2130x; 1.0099x over previous
//
#include <hip/hip_runtime.h>
#include <hip/hip_bf16.h>
#include <math.h>

// Problem: MultiHeadSelfAttention  B=4, S=2048, D=1024, H=16, Hd=64
// fp32 in / fp32 out. bf16 scratch, fp32 accumulation.
// Round 25:
//  - cvt consolidation: cvt_bf16(x) + cvt_w3 merged into ONE launch
//    (cvt_xw3, 5632 blocks). Removes a kernel-boundary gap and lets the
//    small w3 conversion backfill the x-conversion tail. Zero-risk: same
//    per-block code, disjoint in/out, branch on blockIdx.
//  - QKV gemm: R16 exact, frozen (93.5us verified 5x; structure ledger
//    closed: 4w/128^2/8-phase/A-direct/fused-cvt all falsified).
//  - attn: R22-verified (T14 async-stage + LDS dbuf), frozen.
//  - final gemm: R18/R21-verified 128^2/4w, frozen.
// ws: Qb@0, Kb@16M, Vb@32M, Xb/Ob@48M (aliased). Wstash in d_out (dead
// until final GEMM); wo converted into Qb after attention frees it.

#define S_LEN 2048
#define DM    1024
#define NH    16
#define HD    64
#define M_ROWS 8192   // B * S

typedef __attribute__((ext_vector_type(8))) short bf16x8;
typedef __attribute__((ext_vector_type(4))) float f32x4;
typedef __attribute__((ext_vector_type(16))) float f32x16;

__device__ __forceinline__ float bf2f(unsigned short u) {
  union { unsigned int i; float f; } c; c.i = ((unsigned int)u) << 16; return c.f;
}
__device__ __forceinline__ unsigned short f2bf(float f) {
  unsigned int x = __float_as_uint(f);
  if ((x & 0x7fffffffu) > 0x7f800000u) return (unsigned short)0x7fc0u;  // NaN
  return (unsigned short)((x + 0x7fffu + ((x >> 16) & 1u)) >> 16);      // RNE
}
// async global->LDS, 16 B per lane; lds dest must be wave-uniform
__device__ __forceinline__ void gl_lds16(const unsigned short* g, unsigned short* l) {
  __builtin_amdgcn_global_load_lds(
      (const __attribute__((address_space(1))) unsigned int*)g,
      (__attribute__((address_space(3))) unsigned int*)l, 16, 0, 0);
}

#define FENCE() asm volatile("" ::: "memory")

// ---------------------------------------------------------------------------
// fp32 -> bf16 bulk convert (8 elems/thread) — used for wo (post-attention)
// ---------------------------------------------------------------------------
__global__ __launch_bounds__(256) void cvt_bf16(const float* __restrict__ in,
                                                unsigned short* __restrict__ out) {
  const int i = blockIdx.x * 256 + threadIdx.x;
  float4 a = ((const float4*)in)[2 * i];
  float4 b = ((const float4*)in)[2 * i + 1];
  ushort4 r0, r1;
  r0.x = f2bf(a.x); r0.y = f2bf(a.y); r0.z = f2bf(a.z); r0.w = f2bf(a.w);
  r1.x = f2bf(b.x); r1.y = f2bf(b.y); r1.z = f2bf(b.z); r1.w = f2bf(b.w);
  ((ushort4*)out)[2 * i] = r0;
  ((ushort4*)out)[2 * i + 1] = r1;
}

// ---------------------------------------------------------------------------
// Merged prologue convert: blocks [0,4096) convert x (8.4M fp32 -> Xb);
// blocks [4096,5632) convert wq/wk/wv into the contiguous Wstash
// [3072][1024] bf16. Disjoint in/out; one launch.
// ---------------------------------------------------------------------------
__global__ __launch_bounds__(256) void cvt_xw3(const float* __restrict__ x,
                                               unsigned short* __restrict__ xout,
                                               const float* __restrict__ w0,
                                               const float* __restrict__ w1,
                                               const float* __restrict__ w2,
                                               unsigned short* __restrict__ wout) {
  const int bid = blockIdx.x;
  const float* src;
  unsigned short* dst;
  int i;
  if (bid < 4096) {
    src = x;  dst = xout;
    i = bid * 256 + threadIdx.x;
  } else {
    const int idx = bid - 4096;               // 0..1535
    const int which = idx >> 9;
    src = (which == 0) ? w0 : (which == 1) ? w1 : w2;
    dst = wout + (size_t)which * (DM * DM);
    i = (idx & 511) * 256 + threadIdx.x;
  }
  float4 a = ((const float4*)src)[2 * i];
  float4 b = ((const float4*)src)[2 * i + 1];
  ushort4 r0, r1;
  r0.x = f2bf(a.x); r0.y = f2bf(a.y); r0.z = f2bf(a.z); r0.w = f2bf(a.w);
  r1.x = f2bf(b.x); r1.y = f2bf(b.y); r1.z = f2bf(b.z); r1.w = f2bf(b.w);
  ((ushort4*)dst)[2 * i] = r0;
  ((ushort4*)dst)[2 * i + 1] = r1;
}

// ---------------------------------------------------------------------------
// QKV GEMM (R16 exact): counted-vmcnt ring-3, 256x128, 8 waves, 1 bar/K-step.
// C[m,e] = sum_d A[m,d] * Wall[e,d].  bf16 out, z-slab scatter.
// ---------------------------------------------------------------------------
__global__ __launch_bounds__(512, 4) void gemm_qkv(const unsigned short* __restrict__ A,
                                                   const unsigned short* __restrict__ Wall,
                                                   unsigned short* __restrict__ outB) {
  __shared__ __align__(16) unsigned short As[3 * 8192];  // [buf][kgrp4][256][8]
  __shared__ __align__(16) unsigned short Bs[3 * 4096];  // [buf][kgrp4][128][8]
  const int m0 = blockIdx.x * 256;
  const int n0 = blockIdx.y * 128;
  const int tid = threadIdx.x;
  const int lane = tid & 63, w = tid >> 6;
  const int quad = lane >> 4, l15 = lane & 15;
  const int wrow = w >> 1, wcol = w & 1;    // compute mapping: 4M x 2N waves

  const int skg = w & 3, srq = w >> 2;
  const unsigned short* agA = A    + (size_t)(m0 + srq * 64 + lane) * DM + skg * 8;
  const unsigned short* bgB = Wall + (size_t)(n0 + srq * 64 + lane) * DM + skg * 8;
  const int lA0 = skg * 2048 + srq * 512;   // wave-uniform LDS elem offsets
  const int lA1 = lA0 + 1024;               // rows +128
  const int lB  = skg * 1024 + srq * 512;
  const int raA = quad * 2048 + (wrow * 64 + l15) * 8;  // frag-read bases
  const int raB = quad * 1024 + (wcol * 64 + l15) * 8;

  f32x4 acc[4][4];
#pragma unroll
  for (int i = 0; i < 4; ++i)
#pragma unroll
    for (int j = 0; j < 4; ++j) { acc[i][j].x = 0.f; acc[i][j].y = 0.f; acc[i][j].z = 0.f; acc[i][j].w = 0.f; }

#define STAGE3(T, SB) do {                                                   \
    const unsigned short* ap_ = agA + (size_t)(T) * 32;                      \
    gl_lds16(ap_,          &As[(SB) * 8192 + lA0]);                          \
    gl_lds16(ap_ + 131072, &As[(SB) * 8192 + lA1]);                          \
    gl_lds16(bgB + (size_t)(T) * 32, &Bs[(SB) * 4096 + lB]);                 \
  } while (0)

#define COMPUTE(CB) do {                                                     \
    bf16x8 af_[4], bq_[4];                                                   \
    _Pragma("unroll")                                                        \
    for (int mi = 0; mi < 4; ++mi)                                           \
      af_[mi] = *(const bf16x8*)&As[(CB) * 8192 + raA + mi * 128];           \
    _Pragma("unroll")                                                        \
    for (int ni = 0; ni < 4; ++ni)                                           \
      bq_[ni] = *(const bf16x8*)&Bs[(CB) * 4096 + raB + ni * 128];           \
    __builtin_amdgcn_s_setprio(1);                                           \
    _Pragma("unroll")                                                        \
    for (int mi = 0; mi < 4; ++mi)                                           \
      _Pragma("unroll")                                                      \
      for (int ni = 0; ni < 4; ++ni)                                         \
        acc[mi][ni] = __builtin_amdgcn_mfma_f32_16x16x32_bf16(af_[mi], bq_[ni], acc[mi][ni], 0, 0, 0); \
    __builtin_amdgcn_s_setprio(0);                                           \
  } while (0)

#define SUBSTEP(T, SB, CB) do {                                              \
    asm volatile("s_waitcnt vmcnt(3)" ::: "memory");                         \
    __builtin_amdgcn_s_barrier();                                            \
    FENCE();                                                                 \
    STAGE3((T), (SB));                                                       \
    COMPUTE(CB);                                                             \
    FENCE();                                                                 \
  } while (0)

  STAGE3(0, 0);
  STAGE3(1, 1);

  for (int t = 0; t < 30; t += 3) {
    SUBSTEP(t + 2, 2, 0);
    SUBSTEP(t + 3, 0, 1);
    SUBSTEP(t + 4, 1, 2);
  }
  asm volatile("s_waitcnt vmcnt(3)" ::: "memory");
  __builtin_amdgcn_s_barrier();
  FENCE();
  COMPUTE(0);
  asm volatile("s_waitcnt vmcnt(0)" ::: "memory");
  __builtin_amdgcn_s_barrier();
  FENCE();
  COMPUTE(1);

#undef SUBSTEP
#undef COMPUTE
#undef STAGE3

  const float oscale = (n0 < 1024) ? 0.125f : 1.0f;
#pragma unroll
  for (int mi = 0; mi < 4; ++mi) {
#pragma unroll
    for (int reg = 0; reg < 4; ++reg) {
      const int m = m0 + wrow * 64 + mi * 16 + quad * 4 + reg;
#pragma unroll
      for (int ni = 0; ni < 4; ++ni) {
        const int e = n0 + wcol * 64 + ni * 16 + l15;
        const float v = acc[mi][ni][reg];
        const int z = e >> 10;                   // 0:Q 1:K 2:V
        const int e10 = e & 1023;
        const int b = m >> 11, s = m & (S_LEN - 1);
        const int h = e10 >> 6, hd = e10 & 63;
        outB[(size_t)z * (M_ROWS * DM) +
             (((size_t)(b * NH + h)) * S_LEN + s) * HD + hd] = f2bf(v * oscale);
      }
    }
  }
}

// ---------------------------------------------------------------------------
// Final GEMM (R18/R21-verified 128^2/4w): counted-vmcnt ring-3, fp32 out.
// ---------------------------------------------------------------------------
__global__ __launch_bounds__(256, 2) void gemm_out(const unsigned short* __restrict__ A,
                                                   const unsigned short* __restrict__ Wb,
                                                   float* __restrict__ outF) {
  __shared__ __align__(16) unsigned short As[3 * 4096];  // [buf][kgrp4][128][8]
  __shared__ __align__(16) unsigned short Bs[3 * 4096];
  const int m0 = blockIdx.x * 128;
  const int n0 = blockIdx.y * 128;
  const int tid = threadIdx.x;
  const int lane = tid & 63, w = tid >> 6;   // 4 waves
  const int quad = lane >> 4, l15 = lane & 15;
  const int wr = w >> 1, wc = w & 1;         // compute mapping: 2M x 2N waves

  const unsigned short* agA = A  + (size_t)(m0 + lane) * DM + w * 8;
  const unsigned short* bgB = Wb + (size_t)(n0 + lane) * DM + w * 8;
  const int lA0 = w * 1024;                  // elem base (kgrp=w, rows 0..63)
  const int lB0 = w * 1024;
  const int raA = quad * 1024 + (wr * 64 + l15) * 8;  // frag-read bases
  const int raB = quad * 1024 + (wc * 64 + l15) * 8;

  f32x4 acc[4][4];
#pragma unroll
  for (int i = 0; i < 4; ++i)
#pragma unroll
    for (int j = 0; j < 4; ++j) { acc[i][j].x = 0.f; acc[i][j].y = 0.f; acc[i][j].z = 0.f; acc[i][j].w = 0.f; }

#define STAGE4(T, SB) do {                                                   \
    const unsigned short* ap_ = agA + (size_t)(T) * 32;                      \
    const unsigned short* bp_ = bgB + (size_t)(T) * 32;                      \
    gl_lds16(ap_,           &As[(SB) * 4096 + lA0]);                         \
    gl_lds16(ap_ + 64 * DM, &As[(SB) * 4096 + lA0 + 512]);                   \
    gl_lds16(bp_,           &Bs[(SB) * 4096 + lB0]);                         \
    gl_lds16(bp_ + 64 * DM, &Bs[(SB) * 4096 + lB0 + 512]);                   \
  } while (0)

#define COMPUTE(CB) do {                                                     \
    bf16x8 af_[4], bq_[4];                                                   \
    _Pragma("unroll")                                                        \
    for (int mi = 0; mi < 4; ++mi)                                           \
      af_[mi] = *(const bf16x8*)&As[(CB) * 4096 + raA + mi * 128];           \
    _Pragma("unroll")                                                        \
    for (int ni = 0; ni < 4; ++ni)                                           \
      bq_[ni] = *(const bf16x8*)&Bs[(CB) * 4096 + raB + ni * 128];           \
    __builtin_amdgcn_s_setprio(1);                                           \
    _Pragma("unroll")                                                        \
    for (int mi = 0; mi < 4; ++mi)                                           \
      _Pragma("unroll")                                                      \
      for (int ni = 0; ni < 4; ++ni)                                         \
        acc[mi][ni] = __builtin_amdgcn_mfma_f32_16x16x32_bf16(af_[mi], bq_[ni], acc[mi][ni], 0, 0, 0); \
    __builtin_amdgcn_s_setprio(0);                                           \
  } while (0)

#define SUBSTEP(T, SB, CB) do {                                              \
    asm volatile("s_waitcnt vmcnt(4)" ::: "memory");                         \
    __builtin_amdgcn_s_barrier();                                            \
    FENCE();                                                                 \
    STAGE4((T), (SB));                                                       \
    COMPUTE(CB);                                                             \
    FENCE();                                                                 \
  } while (0)

  STAGE4(0, 0);
  STAGE4(1, 1);

  for (int t = 0; t < 30; t += 3) {
    SUBSTEP(t + 2, 2, 0);
    SUBSTEP(t + 3, 0, 1);
    SUBSTEP(t + 4, 1, 2);
  }
  asm volatile("s_waitcnt vmcnt(4)" ::: "memory");
  __builtin_amdgcn_s_barrier();
  FENCE();
  COMPUTE(0);
  asm volatile("s_waitcnt vmcnt(0)" ::: "memory");
  __builtin_amdgcn_s_barrier();
  FENCE();
  COMPUTE(1);

#undef SUBSTEP
#undef COMPUTE
#undef STAGE4

#pragma unroll
  for (int mi = 0; mi < 4; ++mi) {
#pragma unroll
    for (int reg = 0; reg < 4; ++reg) {
      const int m = m0 + wr * 64 + mi * 16 + quad * 4 + reg;
#pragma unroll
      for (int ni = 0; ni < 4; ++ni) {
        const int e = n0 + wc * 64 + ni * 16 + l15;
        outF[(size_t)m * DM + e] = acc[mi][ni][reg];
      }
    }
  }
}

// ---------------------------------------------------------------------------
// MFMA flash attention on 32x32x16, swapped QK^T, in-register softmax+P.
// R22-verified: LDS double-buffered K/V + T14 async-stage; ONE barrier/jt.
// ---------------------------------------------------------------------------
__global__ __launch_bounds__(256, 4) void attn_mfma(const unsigned short* __restrict__ Q,
                                                    const unsigned short* __restrict__ K,
                                                    const unsigned short* __restrict__ V,
                                                    unsigned short* __restrict__ O) {
  __shared__ unsigned short Ks[2][64][72];
  __shared__ unsigned short Vt[2][64][72];
  const int bh = blockIdx.x;                 // 0..63
  const int bx = 15 - (int)blockIdx.y;       // heavy q-blocks dispatched first
  const int tid = threadIdx.x;
  const int w = tid >> 6, lane = tid & 63;
  const int l31 = lane & 31, hi = lane >> 5;
  const size_t base = (size_t)bh * S_LEN * HD;
  const int b = bh >> 4, h = bh & 15;
  const int wq0 = bx * 128 + w * 32;
  const int diag_jt = 2 * bx + (w >> 1);     // wave's last (and partial) tile
  const int jt_blk = 2 * bx + 1;             // block's last tile
  const int kr0 = tid >> 3, kc0 = (tid & 7) * 8;
  const int vs = (tid & 31) * 2, vh = (tid >> 5) * 8;

  // Q fragments (B-operand): lane (hi,q=l31) holds d = ds*16 + hi*8 + e
  bf16x8 qb[4];
#pragma unroll
  for (int ds = 0; ds < 4; ++ds)
    qb[ds] = *(const bf16x8*)(Q + base + (size_t)(wq0 + l31) * HD + ds * 16 + hi * 8);

  f32x16 o0, o1;
#pragma unroll
  for (int r = 0; r < 16; ++r) { o0[r] = 0.f; o1[r] = 0.f; }
  float l_acc = 0.f;

  // prologue: tile 0 -> regs -> buf 0
  uint4 kA, kB, vA, vB;
  {
    const unsigned short* kgp = K + base;
    const unsigned short* vgp = V + base;
    kA = *(const uint4*)(kgp + kr0 * HD + kc0);
    kB = *(const uint4*)(kgp + (kr0 + 32) * HD + kc0);
    vA = *(const uint4*)(vgp + (size_t)vs * HD + vh);
    vB = *(const uint4*)(vgp + (size_t)(vs + 1) * HD + vh);
  }
  {
    *(uint4*)&Ks[0][kr0][kc0]      = kA;
    *(uint4*)&Ks[0][kr0 + 32][kc0] = kB;
    const unsigned int* a0 = (const unsigned int*)&vA;
    const unsigned int* a1 = (const unsigned int*)&vB;
#pragma unroll
    for (int j = 0; j < 4; ++j) {
      *(unsigned int*)&Vt[0][vh + 2 * j][vs]     = __builtin_amdgcn_perm(a1[j], a0[j], 0x05040100u);
      *(unsigned int*)&Vt[0][vh + 2 * j + 1][vs] = __builtin_amdgcn_perm(a1[j], a0[j], 0x07060302u);
    }
  }

  for (int jt = 0; jt <= jt_blk; ++jt) {
    const int cb = jt & 1;
    __syncthreads();   // buf[cb] writes visible; all reads of buf[cb^1] done

    if (jt < jt_blk) {
      const unsigned short* kgp = K + base + (size_t)(jt + 1) * 64 * HD;
      const unsigned short* vgp = V + base + (size_t)(jt + 1) * 64 * HD;
      kA = *(const uint4*)(kgp + kr0 * HD + kc0);
      kB = *(const uint4*)(kgp + (kr0 + 32) * HD + kc0);
      vA = *(const uint4*)(vgp + (size_t)vs * HD + vh);
      vB = *(const uint4*)(vgp + (size_t)(vs + 1) * HD + vh);
    }

    if (jt <= diag_jt) {                      // wave-uniform
      const bool diag = (jt == diag_jt);
      for (int kb = 0; kb < 2; ++kb) {
        const bool kb_zero = diag && ((w & 1) == 0) && (kb == 1);
        const bool kb_part = diag && (kb == (w & 1));
        if (kb_zero) continue;                // wave-uniform; no contribution

        f32x16 sa;
#pragma unroll
        for (int r = 0; r < 16; ++r) sa[r] = 0.f;
        __builtin_amdgcn_s_setprio(1);
#pragma unroll
        for (int ds = 0; ds < 4; ++ds) {
          bf16x8 kf = *(const bf16x8*)&Ks[cb][kb * 32 + l31][ds * 16 + hi * 8];
          sa = __builtin_amdgcn_mfma_f32_32x32x16_bf16(kf, qb[ds], sa, 0, 0, 0);
        }
        __builtin_amdgcn_s_setprio(0);

        float p[16];
        if (kb_part) {
#pragma unroll
          for (int r = 0; r < 16; ++r) {
            const int krel = (r & 3) + 8 * (r >> 2) + 4 * hi;
            p[r] = __expf((l31 >= krel) ? sa[r] : -1.0e30f);
          }
        } else {
#pragma unroll
          for (int r = 0; r < 16; ++r) p[r] = __expf(sa[r]);
        }
        l_acc += (((p[0] + p[1]) + (p[2] + p[3])) + ((p[4] + p[5]) + (p[6] + p[7])))
               + (((p[8] + p[9]) + (p[10] + p[11])) + ((p[12] + p[13]) + (p[14] + p[15])));

        unsigned int pk[8], sk[8];
#pragma unroll
        for (int g = 0; g < 4; ++g) {
          pk[2 * g]     = __builtin_amdgcn_perm(__float_as_uint(p[4 * g + 1]), __float_as_uint(p[4 * g]),     0x07060302u);
          pk[2 * g + 1] = __builtin_amdgcn_perm(__float_as_uint(p[4 * g + 3]), __float_as_uint(p[4 * g + 2]), 0x07060302u);
        }
#pragma unroll
        for (int i = 0; i < 8; ++i) sk[i] = (unsigned int)__shfl_xor((int)pk[i], 32);

#pragma unroll
        for (int sl = 0; sl < 2; ++sl) {
          const int g0 = 2 * sl, g1 = 2 * sl + 1;
          union { unsigned int u[4]; bf16x8 v; } fa;
          fa.u[0] = hi ? sk[2 * g1]     : pk[2 * g0];
          fa.u[1] = hi ? sk[2 * g1 + 1] : pk[2 * g0 + 1];
          fa.u[2] = hi ? pk[2 * g1]     : sk[2 * g0];
          fa.u[3] = hi ? pk[2 * g1 + 1] : sk[2 * g0 + 1];
          const int s = kb * 2 + sl;
          bf16x8 v0 = *(const bf16x8*)&Vt[cb][l31][s * 16 + hi * 8];
          bf16x8 v1 = *(const bf16x8*)&Vt[cb][32 + l31][s * 16 + hi * 8];
          __builtin_amdgcn_s_setprio(1);
          o0 = __builtin_amdgcn_mfma_f32_32x32x16_bf16(fa.v, v0, o0, 0, 0, 0);
          o1 = __builtin_amdgcn_mfma_f32_32x32x16_bf16(fa.v, v1, o1, 0, 0, 0);
          __builtin_amdgcn_s_setprio(0);
        }
      }
    }

    if (jt < jt_blk) {
      const int nb = cb ^ 1;
      *(uint4*)&Ks[nb][kr0][kc0]      = kA;
      *(uint4*)&Ks[nb][kr0 + 32][kc0] = kB;
      const unsigned int* a0 = (const unsigned int*)&vA;
      const unsigned int* a1 = (const unsigned int*)&vB;
#pragma unroll
      for (int j = 0; j < 4; ++j) {
        *(unsigned int*)&Vt[nb][vh + 2 * j][vs]     = __builtin_amdgcn_perm(a1[j], a0[j], 0x05040100u);
        *(unsigned int*)&Vt[nb][vh + 2 * j + 1][vs] = __builtin_amdgcn_perm(a1[j], a0[j], 0x07060302u);
      }
    }
  }

  // epilogue: l total (xor32 joins the two k-halves), scale + write O
  const float lf = l_acc + __shfl_xor(l_acc, 32);
  const float inv = 1.0f / lf;
#pragma unroll
  for (int r = 0; r < 16; ++r) {
    const int qrel = (r & 3) + 8 * (r >> 2) + 4 * hi;
    const float invr = __shfl(inv, qrel);    // lane qrel holds l for q=wq0+qrel
    const size_t orow = (size_t)(b * S_LEN + wq0 + qrel) * DM + h * HD;
    O[orow + l31]      = f2bf(o0[r] * invr);
    O[orow + 32 + l31] = f2bf(o1[r] * invr);
  }
}

extern "C" void kernel_launch(void* const* d_in, const int* in_sizes, int n_in,
                              void* d_out, int out_size, void* d_ws, size_t ws_size,
                              hipStream_t stream) {
  const float* x  = (const float*)d_in[0];  // fp32 [4,2048,1024]
  const float* wq = (const float*)d_in[1];  // fp32 [1024,1024]
  const float* wk = (const float*)d_in[2];
  const float* wv = (const float*)d_in[3];
  const float* wo = (const float*)d_in[4];

  unsigned short* Qb = (unsigned short*)d_ws;                 // 16 MB
  unsigned short* Kb = Qb + (size_t)M_ROWS * DM;              // 16 MB (Qb+z*16M)
  unsigned short* Vb = Kb + (size_t)M_ROWS * DM;              // 16 MB
  unsigned short* Xb = Vb + (size_t)M_ROWS * DM;              // 16 MB (alias Ob)
  unsigned short* Ob = Xb;
  (void)Kb; (void)Vb;

  // bf16 weight stash inside d_out (32 MB fp32 buffer; dead until final GEMM)
  unsigned short* Wstash = (unsigned short*)d_out;            // [3072][1024] bf16

  dim3 bb(256);
  dim3 gb(512);

  // merged prologue: x -> Xb and wq/wk/wv -> Wstash in ONE launch
  hipLaunchKernelGGL(cvt_xw3, dim3(4096 + 1536), bb, 0, stream,
                     x, Xb, wq, wk, wv, Wstash);
  // fused QKV as single GEMM: M=8192, N=3072 (z = e>>10 selects output slab)
  hipLaunchKernelGGL(gemm_qkv, dim3(M_ROWS / 256, 3 * DM / 128), gb, 0, stream,
                     Xb, Wstash, Qb);
  hipLaunchKernelGGL(attn_mfma, dim3(64, 16), bb, 0, stream, Qb, Qb + (size_t)M_ROWS * DM,
                     Qb + 2 * (size_t)M_ROWS * DM, Ob);
  // wo -> bf16 into Qb (free after attention); then final projection
  hipLaunchKernelGGL(cvt_bf16, dim3((DM * DM) / 2048), bb, 0, stream, wo, Qb);
  hipLaunchKernelGGL(gemm_out, dim3(M_ROWS / 128, DM / 128), bb, 0, stream,
                     Ob, Qb, (float*)d_out);
}

// Round 17
// 191.194 us; speedup vs baseline: 1.2219x; 1.0073x over previous
//
#include <hip/hip_runtime.h>
#include <hip/hip_bf16.h>
#include <math.h>

// Problem: MultiHeadSelfAttention  B=4, S=2048, D=1024, H=16, Hd=64
// fp32 in / fp32 out. bf16 scratch, fp32 accumulation.
// Round 26:
//  - wo-cvt fusion (ws_size-conditional): if ws has >=2MB slack past our
//    64MB layout, attn's 1024 blocks each convert 1024 wo elems at entry
//    (1 float4/thread, overlapped with attention) into ws+64MB; gemm_out
//    reads W there (kernel-boundary ordered). Removes the standalone
//    cvt_bf16(wo) launch + gaps. If ws_size < 66MB: exact R25 path
//    (runtime branch in launcher; zero risk).
//  - cvt_xw3 merged prologue: R25-verified.
//  - QKV gemm: R16 exact, frozen (93.5us verified 6x).
//  - attn: R22-verified core (T14 async-stage + LDS dbuf), frozen.
//  - final gemm: R18/R21-verified 128^2/4w, frozen.
// ws: Qb@0, Kb@16M, Vb@32M, Xb/Ob@48M (aliased), WoB@64M (if slack).
// Wstash in d_out (dead until final GEMM).

#define S_LEN 2048
#define DM    1024
#define NH    16
#define HD    64
#define M_ROWS 8192   // B * S

typedef __attribute__((ext_vector_type(8))) short bf16x8;
typedef __attribute__((ext_vector_type(4))) float f32x4;
typedef __attribute__((ext_vector_type(16))) float f32x16;

__device__ __forceinline__ float bf2f(unsigned short u) {
  union { unsigned int i; float f; } c; c.i = ((unsigned int)u) << 16; return c.f;
}
__device__ __forceinline__ unsigned short f2bf(float f) {
  unsigned int x = __float_as_uint(f);
  if ((x & 0x7fffffffu) > 0x7f800000u) return (unsigned short)0x7fc0u;  // NaN
  return (unsigned short)((x + 0x7fffu + ((x >> 16) & 1u)) >> 16);      // RNE
}
// async global->LDS, 16 B per lane; lds dest must be wave-uniform
__device__ __forceinline__ void gl_lds16(const unsigned short* g, unsigned short* l) {
  __builtin_amdgcn_global_load_lds(
      (const __attribute__((address_space(1))) unsigned int*)g,
      (__attribute__((address_space(3))) unsigned int*)l, 16, 0, 0);
}

#define FENCE() asm volatile("" ::: "memory")

// ---------------------------------------------------------------------------
// fp32 -> bf16 bulk convert (8 elems/thread) — fallback path for wo
// ---------------------------------------------------------------------------
__global__ __launch_bounds__(256) void cvt_bf16(const float* __restrict__ in,
                                                unsigned short* __restrict__ out) {
  const int i = blockIdx.x * 256 + threadIdx.x;
  float4 a = ((const float4*)in)[2 * i];
  float4 b = ((const float4*)in)[2 * i + 1];
  ushort4 r0, r1;
  r0.x = f2bf(a.x); r0.y = f2bf(a.y); r0.z = f2bf(a.z); r0.w = f2bf(a.w);
  r1.x = f2bf(b.x); r1.y = f2bf(b.y); r1.z = f2bf(b.z); r1.w = f2bf(b.w);
  ((ushort4*)out)[2 * i] = r0;
  ((ushort4*)out)[2 * i + 1] = r1;
}

// ---------------------------------------------------------------------------
// Merged prologue convert: blocks [0,4096) convert x (8.4M fp32 -> Xb);
// blocks [4096,5632) convert wq/wk/wv into the contiguous Wstash
// [3072][1024] bf16. Disjoint in/out; one launch. (R25-verified)
// ---------------------------------------------------------------------------
__global__ __launch_bounds__(256) void cvt_xw3(const float* __restrict__ x,
                                               unsigned short* __restrict__ xout,
                                               const float* __restrict__ w0,
                                               const float* __restrict__ w1,
                                               const float* __restrict__ w2,
                                               unsigned short* __restrict__ wout) {
  const int bid = blockIdx.x;
  const float* src;
  unsigned short* dst;
  int i;
  if (bid < 4096) {
    src = x;  dst = xout;
    i = bid * 256 + threadIdx.x;
  } else {
    const int idx = bid - 4096;               // 0..1535
    const int which = idx >> 9;
    src = (which == 0) ? w0 : (which == 1) ? w1 : w2;
    dst = wout + (size_t)which * (DM * DM);
    i = (idx & 511) * 256 + threadIdx.x;
  }
  float4 a = ((const float4*)src)[2 * i];
  float4 b = ((const float4*)src)[2 * i + 1];
  ushort4 r0, r1;
  r0.x = f2bf(a.x); r0.y = f2bf(a.y); r0.z = f2bf(a.z); r0.w = f2bf(a.w);
  r1.x = f2bf(b.x); r1.y = f2bf(b.y); r1.z = f2bf(b.z); r1.w = f2bf(b.w);
  ((ushort4*)dst)[2 * i] = r0;
  ((ushort4*)dst)[2 * i + 1] = r1;
}

// ---------------------------------------------------------------------------
// QKV GEMM (R16 exact): counted-vmcnt ring-3, 256x128, 8 waves, 1 bar/K-step.
// C[m,e] = sum_d A[m,d] * Wall[e,d].  bf16 out, z-slab scatter.
// ---------------------------------------------------------------------------
__global__ __launch_bounds__(512, 4) void gemm_qkv(const unsigned short* __restrict__ A,
                                                   const unsigned short* __restrict__ Wall,
                                                   unsigned short* __restrict__ outB) {
  __shared__ __align__(16) unsigned short As[3 * 8192];  // [buf][kgrp4][256][8]
  __shared__ __align__(16) unsigned short Bs[3 * 4096];  // [buf][kgrp4][128][8]
  const int m0 = blockIdx.x * 256;
  const int n0 = blockIdx.y * 128;
  const int tid = threadIdx.x;
  const int lane = tid & 63, w = tid >> 6;
  const int quad = lane >> 4, l15 = lane & 15;
  const int wrow = w >> 1, wcol = w & 1;    // compute mapping: 4M x 2N waves

  const int skg = w & 3, srq = w >> 2;
  const unsigned short* agA = A    + (size_t)(m0 + srq * 64 + lane) * DM + skg * 8;
  const unsigned short* bgB = Wall + (size_t)(n0 + srq * 64 + lane) * DM + skg * 8;
  const int lA0 = skg * 2048 + srq * 512;   // wave-uniform LDS elem offsets
  const int lA1 = lA0 + 1024;               // rows +128
  const int lB  = skg * 1024 + srq * 512;
  const int raA = quad * 2048 + (wrow * 64 + l15) * 8;  // frag-read bases
  const int raB = quad * 1024 + (wcol * 64 + l15) * 8;

  f32x4 acc[4][4];
#pragma unroll
  for (int i = 0; i < 4; ++i)
#pragma unroll
    for (int j = 0; j < 4; ++j) { acc[i][j].x = 0.f; acc[i][j].y = 0.f; acc[i][j].z = 0.f; acc[i][j].w = 0.f; }

#define STAGE3(T, SB) do {                                                   \
    const unsigned short* ap_ = agA + (size_t)(T) * 32;                      \
    gl_lds16(ap_,          &As[(SB) * 8192 + lA0]);                          \
    gl_lds16(ap_ + 131072, &As[(SB) * 8192 + lA1]);                          \
    gl_lds16(bgB + (size_t)(T) * 32, &Bs[(SB) * 4096 + lB]);                 \
  } while (0)

#define COMPUTE(CB) do {                                                     \
    bf16x8 af_[4], bq_[4];                                                   \
    _Pragma("unroll")                                                        \
    for (int mi = 0; mi < 4; ++mi)                                           \
      af_[mi] = *(const bf16x8*)&As[(CB) * 8192 + raA + mi * 128];           \
    _Pragma("unroll")                                                        \
    for (int ni = 0; ni < 4; ++ni)                                           \
      bq_[ni] = *(const bf16x8*)&Bs[(CB) * 4096 + raB + ni * 128];           \
    __builtin_amdgcn_s_setprio(1);                                           \
    _Pragma("unroll")                                                        \
    for (int mi = 0; mi < 4; ++mi)                                           \
      _Pragma("unroll")                                                      \
      for (int ni = 0; ni < 4; ++ni)                                         \
        acc[mi][ni] = __builtin_amdgcn_mfma_f32_16x16x32_bf16(af_[mi], bq_[ni], acc[mi][ni], 0, 0, 0); \
    __builtin_amdgcn_s_setprio(0);                                           \
  } while (0)

#define SUBSTEP(T, SB, CB) do {                                              \
    asm volatile("s_waitcnt vmcnt(3)" ::: "memory");                         \
    __builtin_amdgcn_s_barrier();                                            \
    FENCE();                                                                 \
    STAGE3((T), (SB));                                                       \
    COMPUTE(CB);                                                             \
    FENCE();                                                                 \
  } while (0)

  STAGE3(0, 0);
  STAGE3(1, 1);

  for (int t = 0; t < 30; t += 3) {
    SUBSTEP(t + 2, 2, 0);
    SUBSTEP(t + 3, 0, 1);
    SUBSTEP(t + 4, 1, 2);
  }
  asm volatile("s_waitcnt vmcnt(3)" ::: "memory");
  __builtin_amdgcn_s_barrier();
  FENCE();
  COMPUTE(0);
  asm volatile("s_waitcnt vmcnt(0)" ::: "memory");
  __builtin_amdgcn_s_barrier();
  FENCE();
  COMPUTE(1);

#undef SUBSTEP
#undef COMPUTE
#undef STAGE3

  const float oscale = (n0 < 1024) ? 0.125f : 1.0f;
#pragma unroll
  for (int mi = 0; mi < 4; ++mi) {
#pragma unroll
    for (int reg = 0; reg < 4; ++reg) {
      const int m = m0 + wrow * 64 + mi * 16 + quad * 4 + reg;
#pragma unroll
      for (int ni = 0; ni < 4; ++ni) {
        const int e = n0 + wcol * 64 + ni * 16 + l15;
        const float v = acc[mi][ni][reg];
        const int z = e >> 10;                   // 0:Q 1:K 2:V
        const int e10 = e & 1023;
        const int b = m >> 11, s = m & (S_LEN - 1);
        const int h = e10 >> 6, hd = e10 & 63;
        outB[(size_t)z * (M_ROWS * DM) +
             (((size_t)(b * NH + h)) * S_LEN + s) * HD + hd] = f2bf(v * oscale);
      }
    }
  }
}

// ---------------------------------------------------------------------------
// Final GEMM (R18/R21-verified 128^2/4w): counted-vmcnt ring-3, fp32 out.
// ---------------------------------------------------------------------------
__global__ __launch_bounds__(256, 2) void gemm_out(const unsigned short* __restrict__ A,
                                                   const unsigned short* __restrict__ Wb,
                                                   float* __restrict__ outF) {
  __shared__ __align__(16) unsigned short As[3 * 4096];  // [buf][kgrp4][128][8]
  __shared__ __align__(16) unsigned short Bs[3 * 4096];
  const int m0 = blockIdx.x * 128;
  const int n0 = blockIdx.y * 128;
  const int tid = threadIdx.x;
  const int lane = tid & 63, w = tid >> 6;   // 4 waves
  const int quad = lane >> 4, l15 = lane & 15;
  const int wr = w >> 1, wc = w & 1;         // compute mapping: 2M x 2N waves

  const unsigned short* agA = A  + (size_t)(m0 + lane) * DM + w * 8;
  const unsigned short* bgB = Wb + (size_t)(n0 + lane) * DM + w * 8;
  const int lA0 = w * 1024;                  // elem base (kgrp=w, rows 0..63)
  const int lB0 = w * 1024;
  const int raA = quad * 1024 + (wr * 64 + l15) * 8;  // frag-read bases
  const int raB = quad * 1024 + (wc * 64 + l15) * 8;

  f32x4 acc[4][4];
#pragma unroll
  for (int i = 0; i < 4; ++i)
#pragma unroll
    for (int j = 0; j < 4; ++j) { acc[i][j].x = 0.f; acc[i][j].y = 0.f; acc[i][j].z = 0.f; acc[i][j].w = 0.f; }

#define STAGE4(T, SB) do {                                                   \
    const unsigned short* ap_ = agA + (size_t)(T) * 32;                      \
    const unsigned short* bp_ = bgB + (size_t)(T) * 32;                      \
    gl_lds16(ap_,           &As[(SB) * 4096 + lA0]);                         \
    gl_lds16(ap_ + 64 * DM, &As[(SB) * 4096 + lA0 + 512]);                   \
    gl_lds16(bp_,           &Bs[(SB) * 4096 + lB0]);                         \
    gl_lds16(bp_ + 64 * DM, &Bs[(SB) * 4096 + lB0 + 512]);                   \
  } while (0)

#define COMPUTE(CB) do {                                                     \
    bf16x8 af_[4], bq_[4];                                                   \
    _Pragma("unroll")                                                        \
    for (int mi = 0; mi < 4; ++mi)                                           \
      af_[mi] = *(const bf16x8*)&As[(CB) * 4096 + raA + mi * 128];           \
    _Pragma("unroll")                                                        \
    for (int ni = 0; ni < 4; ++ni)                                           \
      bq_[ni] = *(const bf16x8*)&Bs[(CB) * 4096 + raB + ni * 128];           \
    __builtin_amdgcn_s_setprio(1);                                           \
    _Pragma("unroll")                                                        \
    for (int mi = 0; mi < 4; ++mi)                                           \
      _Pragma("unroll")                                                      \
      for (int ni = 0; ni < 4; ++ni)                                         \
        acc[mi][ni] = __builtin_amdgcn_mfma_f32_16x16x32_bf16(af_[mi], bq_[ni], acc[mi][ni], 0, 0, 0); \
    __builtin_amdgcn_s_setprio(0);                                           \
  } while (0)

#define SUBSTEP(T, SB, CB) do {                                              \
    asm volatile("s_waitcnt vmcnt(4)" ::: "memory");                         \
    __builtin_amdgcn_s_barrier();                                            \
    FENCE();                                                                 \
    STAGE4((T), (SB));                                                       \
    COMPUTE(CB);                                                             \
    FENCE();                                                                 \
  } while (0)

  STAGE4(0, 0);
  STAGE4(1, 1);

  for (int t = 0; t < 30; t += 3) {
    SUBSTEP(t + 2, 2, 0);
    SUBSTEP(t + 3, 0, 1);
    SUBSTEP(t + 4, 1, 2);
  }
  asm volatile("s_waitcnt vmcnt(4)" ::: "memory");
  __builtin_amdgcn_s_barrier();
  FENCE();
  COMPUTE(0);
  asm volatile("s_waitcnt vmcnt(0)" ::: "memory");
  __builtin_amdgcn_s_barrier();
  FENCE();
  COMPUTE(1);

#undef SUBSTEP
#undef COMPUTE
#undef STAGE4

#pragma unroll
  for (int mi = 0; mi < 4; ++mi) {
#pragma unroll
    for (int reg = 0; reg < 4; ++reg) {
      const int m = m0 + wr * 64 + mi * 16 + quad * 4 + reg;
#pragma unroll
      for (int ni = 0; ni < 4; ++ni) {
        const int e = n0 + wc * 64 + ni * 16 + l15;
        outF[(size_t)m * DM + e] = acc[mi][ni][reg];
      }
    }
  }
}

// ---------------------------------------------------------------------------
// MFMA flash attention on 32x32x16, swapped QK^T, in-register softmax+P.
// R22-verified core. R26: optional fused wo fp32->bf16 conversion at entry
// (wo_src/wo_dst non-null): each of 1024 blocks converts 1024 elems into
// untouched ws slack; fully overlapped with attention; consumed by gemm_out
// after the kernel boundary.
// ---------------------------------------------------------------------------
__global__ __launch_bounds__(256, 4) void attn_mfma(const unsigned short* __restrict__ Q,
                                                    const unsigned short* __restrict__ K,
                                                    const unsigned short* __restrict__ V,
                                                    unsigned short* __restrict__ O,
                                                    const float* __restrict__ wo_src,
                                                    unsigned short* __restrict__ wo_dst) {
  __shared__ unsigned short Ks[2][64][72];
  __shared__ unsigned short Vt[2][64][72];
  const int bh = blockIdx.x;                 // 0..63
  const int bx = 15 - (int)blockIdx.y;       // heavy q-blocks dispatched first
  const int tid = threadIdx.x;

  // optional fused wo conversion (1 float4 per thread, disjoint memory)
  if (wo_src != nullptr) {
    const int flat = bh * 16 + (int)blockIdx.y;      // 0..1023
    const int i = flat * 256 + tid;                  // float4 index, 1M/4 total
    float4 a = ((const float4*)wo_src)[i];
    ushort4 r;
    r.x = f2bf(a.x); r.y = f2bf(a.y); r.z = f2bf(a.z); r.w = f2bf(a.w);
    ((ushort4*)wo_dst)[i] = r;
  }

  const int w = tid >> 6, lane = tid & 63;
  const int l31 = lane & 31, hi = lane >> 5;
  const size_t base = (size_t)bh * S_LEN * HD;
  const int b = bh >> 4, h = bh & 15;
  const int wq0 = bx * 128 + w * 32;
  const int diag_jt = 2 * bx + (w >> 1);     // wave's last (and partial) tile
  const int jt_blk = 2 * bx + 1;             // block's last tile
  const int kr0 = tid >> 3, kc0 = (tid & 7) * 8;
  const int vs = (tid & 31) * 2, vh = (tid >> 5) * 8;

  // Q fragments (B-operand): lane (hi,q=l31) holds d = ds*16 + hi*8 + e
  bf16x8 qb[4];
#pragma unroll
  for (int ds = 0; ds < 4; ++ds)
    qb[ds] = *(const bf16x8*)(Q + base + (size_t)(wq0 + l31) * HD + ds * 16 + hi * 8);

  f32x16 o0, o1;
#pragma unroll
  for (int r = 0; r < 16; ++r) { o0[r] = 0.f; o1[r] = 0.f; }
  float l_acc = 0.f;

  // prologue: tile 0 -> regs -> buf 0
  uint4 kA, kB, vA, vB;
  {
    const unsigned short* kgp = K + base;
    const unsigned short* vgp = V + base;
    kA = *(const uint4*)(kgp + kr0 * HD + kc0);
    kB = *(const uint4*)(kgp + (kr0 + 32) * HD + kc0);
    vA = *(const uint4*)(vgp + (size_t)vs * HD + vh);
    vB = *(const uint4*)(vgp + (size_t)(vs + 1) * HD + vh);
  }
  {
    *(uint4*)&Ks[0][kr0][kc0]      = kA;
    *(uint4*)&Ks[0][kr0 + 32][kc0] = kB;
    const unsigned int* a0 = (const unsigned int*)&vA;
    const unsigned int* a1 = (const unsigned int*)&vB;
#pragma unroll
    for (int j = 0; j < 4; ++j) {
      *(unsigned int*)&Vt[0][vh + 2 * j][vs]     = __builtin_amdgcn_perm(a1[j], a0[j], 0x05040100u);
      *(unsigned int*)&Vt[0][vh + 2 * j + 1][vs] = __builtin_amdgcn_perm(a1[j], a0[j], 0x07060302u);
    }
  }

  for (int jt = 0; jt <= jt_blk; ++jt) {
    const int cb = jt & 1;
    __syncthreads();   // buf[cb] writes visible; all reads of buf[cb^1] done

    if (jt < jt_blk) {
      const unsigned short* kgp = K + base + (size_t)(jt + 1) * 64 * HD;
      const unsigned short* vgp = V + base + (size_t)(jt + 1) * 64 * HD;
      kA = *(const uint4*)(kgp + kr0 * HD + kc0);
      kB = *(const uint4*)(kgp + (kr0 + 32) * HD + kc0);
      vA = *(const uint4*)(vgp + (size_t)vs * HD + vh);
      vB = *(const uint4*)(vgp + (size_t)(vs + 1) * HD + vh);
    }

    if (jt <= diag_jt) {                      // wave-uniform
      const bool diag = (jt == diag_jt);
      for (int kb = 0; kb < 2; ++kb) {
        const bool kb_zero = diag && ((w & 1) == 0) && (kb == 1);
        const bool kb_part = diag && (kb == (w & 1));
        if (kb_zero) continue;                // wave-uniform; no contribution

        f32x16 sa;
#pragma unroll
        for (int r = 0; r < 16; ++r) sa[r] = 0.f;
        __builtin_amdgcn_s_setprio(1);
#pragma unroll
        for (int ds = 0; ds < 4; ++ds) {
          bf16x8 kf = *(const bf16x8*)&Ks[cb][kb * 32 + l31][ds * 16 + hi * 8];
          sa = __builtin_amdgcn_mfma_f32_32x32x16_bf16(kf, qb[ds], sa, 0, 0, 0);
        }
        __builtin_amdgcn_s_setprio(0);

        float p[16];
        if (kb_part) {
#pragma unroll
          for (int r = 0; r < 16; ++r) {
            const int krel = (r & 3) + 8 * (r >> 2) + 4 * hi;
            p[r] = __expf((l31 >= krel) ? sa[r] : -1.0e30f);
          }
        } else {
#pragma unroll
          for (int r = 0; r < 16; ++r) p[r] = __expf(sa[r]);
        }
        l_acc += (((p[0] + p[1]) + (p[2] + p[3])) + ((p[4] + p[5]) + (p[6] + p[7])))
               + (((p[8] + p[9]) + (p[10] + p[11])) + ((p[12] + p[13]) + (p[14] + p[15])));

        unsigned int pk[8], sk[8];
#pragma unroll
        for (int g = 0; g < 4; ++g) {
          pk[2 * g]     = __builtin_amdgcn_perm(__float_as_uint(p[4 * g + 1]), __float_as_uint(p[4 * g]),     0x07060302u);
          pk[2 * g + 1] = __builtin_amdgcn_perm(__float_as_uint(p[4 * g + 3]), __float_as_uint(p[4 * g + 2]), 0x07060302u);
        }
#pragma unroll
        for (int i = 0; i < 8; ++i) sk[i] = (unsigned int)__shfl_xor((int)pk[i], 32);

#pragma unroll
        for (int sl = 0; sl < 2; ++sl) {
          const int g0 = 2 * sl, g1 = 2 * sl + 1;
          union { unsigned int u[4]; bf16x8 v; } fa;
          fa.u[0] = hi ? sk[2 * g1]     : pk[2 * g0];
          fa.u[1] = hi ? sk[2 * g1 + 1] : pk[2 * g0 + 1];
          fa.u[2] = hi ? pk[2 * g1]     : sk[2 * g0];
          fa.u[3] = hi ? pk[2 * g1 + 1] : sk[2 * g0 + 1];
          const int s = kb * 2 + sl;
          bf16x8 v0 = *(const bf16x8*)&Vt[cb][l31][s * 16 + hi * 8];
          bf16x8 v1 = *(const bf16x8*)&Vt[cb][32 + l31][s * 16 + hi * 8];
          __builtin_amdgcn_s_setprio(1);
          o0 = __builtin_amdgcn_mfma_f32_32x32x16_bf16(fa.v, v0, o0, 0, 0, 0);
          o1 = __builtin_amdgcn_mfma_f32_32x32x16_bf16(fa.v, v1, o1, 0, 0, 0);
          __builtin_amdgcn_s_setprio(0);
        }
      }
    }

    if (jt < jt_blk) {
      const int nb = cb ^ 1;
      *(uint4*)&Ks[nb][kr0][kc0]      = kA;
      *(uint4*)&Ks[nb][kr0 + 32][kc0] = kB;
      const unsigned int* a0 = (const unsigned int*)&vA;
      const unsigned int* a1 = (const unsigned int*)&vB;
#pragma unroll
      for (int j = 0; j < 4; ++j) {
        *(unsigned int*)&Vt[nb][vh + 2 * j][vs]     = __builtin_amdgcn_perm(a1[j], a0[j], 0x05040100u);
        *(unsigned int*)&Vt[nb][vh + 2 * j + 1][vs] = __builtin_amdgcn_perm(a1[j], a0[j], 0x07060302u);
      }
    }
  }

  // epilogue: l total (xor32 joins the two k-halves), scale + write O
  const float lf = l_acc + __shfl_xor(l_acc, 32);
  const float inv = 1.0f / lf;
#pragma unroll
  for (int r = 0; r < 16; ++r) {
    const int qrel = (r & 3) + 8 * (r >> 2) + 4 * hi;
    const float invr = __shfl(inv, qrel);    // lane qrel holds l for q=wq0+qrel
    const size_t orow = (size_t)(b * S_LEN + wq0 + qrel) * DM + h * HD;
    O[orow + l31]      = f2bf(o0[r] * invr);
    O[orow + 32 + l31] = f2bf(o1[r] * invr);
  }
}

extern "C" void kernel_launch(void* const* d_in, const int* in_sizes, int n_in,
                              void* d_out, int out_size, void* d_ws, size_t ws_size,
                              hipStream_t stream) {
  const float* x  = (const float*)d_in[0];  // fp32 [4,2048,1024]
  const float* wq = (const float*)d_in[1];  // fp32 [1024,1024]
  const float* wk = (const float*)d_in[2];
  const float* wv = (const float*)d_in[3];
  const float* wo = (const float*)d_in[4];

  unsigned short* Qb = (unsigned short*)d_ws;                 // 16 MB
  unsigned short* Kb = Qb + (size_t)M_ROWS * DM;              // 16 MB (Qb+z*16M)
  unsigned short* Vb = Kb + (size_t)M_ROWS * DM;              // 16 MB
  unsigned short* Xb = Vb + (size_t)M_ROWS * DM;              // 16 MB (alias Ob)
  unsigned short* Ob = Xb;
  (void)Kb; (void)Vb;

  // bf16 weight stash inside d_out (32 MB fp32 buffer; dead until final GEMM)
  unsigned short* Wstash = (unsigned short*)d_out;            // [3072][1024] bf16

  // wo-bf16 destination: ws slack at 64MB if available (fused into attn),
  // else Qb after attention (separate launch, exact R25 path)
  const size_t used = (size_t)4 * M_ROWS * DM * sizeof(unsigned short); // 64MB
  const bool fuse_wo = ws_size >= used + (size_t)DM * DM * sizeof(unsigned short);
  unsigned short* WoB = fuse_wo ? (unsigned short*)d_ws + 4 * (size_t)M_ROWS * DM
                                : Qb;

  dim3 bb(256);
  dim3 gb(512);

  // merged prologue: x -> Xb and wq/wk/wv -> Wstash in ONE launch
  hipLaunchKernelGGL(cvt_xw3, dim3(4096 + 1536), bb, 0, stream,
                     x, Xb, wq, wk, wv, Wstash);
  // fused QKV as single GEMM: M=8192, N=3072 (z = e>>10 selects output slab)
  hipLaunchKernelGGL(gemm_qkv, dim3(M_ROWS / 256, 3 * DM / 128), gb, 0, stream,
                     Xb, Wstash, Qb);
  hipLaunchKernelGGL(attn_mfma, dim3(64, 16), bb, 0, stream, Qb, Qb + (size_t)M_ROWS * DM,
                     Qb + 2 * (size_t)M_ROWS * DM, Ob,
                     fuse_wo ? wo : (const float*)nullptr,
                     fuse_wo ? WoB : (unsigned short*)nullptr);
  if (!fuse_wo)
    hipLaunchKernelGGL(cvt_bf16, dim3((DM * DM) / 2048), bb, 0, stream, wo, WoB);
  hipLaunchKernelGGL(gemm_out, dim3(M_ROWS / 128, DM / 128), bb, 0, stream,
                     Ob, WoB, (float*)d_out);
}